// Round 2
// baseline (430.806 us; speedup 1.0000x reference)
//
#include <hip/hip_runtime.h>

#define CH 512
#define HEADS 4
#define HD 128
#define NPIX 1024
#define BATCH 16
#define GROUPS 32
#define GSZ 16
#define EPS 1e-5f

typedef _Float16 f16;
typedef _Float16 f16x8 __attribute__((ext_vector_type(8)));
typedef _Float16 f16x4 __attribute__((ext_vector_type(4)));
typedef float f32x4 __attribute__((ext_vector_type(4)));

// ---------------- K0: convert weights fp32 -> fp16 ----------------
__global__ void k_convert(const float* __restrict__ wq, const float* __restrict__ wp,
                          f16* __restrict__ wq16, f16* __restrict__ wp16) {
    int i = blockIdx.x * 256 + threadIdx.x;
    if (i < 3 * CH * CH) wq16[i] = (f16)wq[i];
    if (i < CH * CH)     wp16[i] = (f16)wp[i];
}

// ---------------- K1a: groupnorm stats (mean, rstd) per (b,g) ----------------
__global__ void k_stats(const float* __restrict__ x, float2* __restrict__ stats) {
    int bg = blockIdx.x;
    const f32x4* b4 = (const f32x4*)(x + (size_t)bg * (GSZ * NPIX));
    float s = 0.f, ss = 0.f;
    for (int i = threadIdx.x; i < GSZ * NPIX / 4; i += 256) {
        f32x4 v = b4[i];
        s  += v.x + v.y + v.z + v.w;
        ss += v.x * v.x + v.y * v.y + v.z * v.z + v.w * v.w;
    }
    for (int off = 32; off; off >>= 1) { s += __shfl_down(s, off); ss += __shfl_down(ss, off); }
    __shared__ float as_[4], ass[4];
    int wv = threadIdx.x >> 6, ln = threadIdx.x & 63;
    if (ln == 0) { as_[wv] = s; ass[wv] = ss; }
    __syncthreads();
    if (threadIdx.x == 0) {
        float S = as_[0] + as_[1] + as_[2] + as_[3];
        float SS = ass[0] + ass[1] + ass[2] + ass[3];
        float mu = S / (GSZ * NPIX);
        float var = SS / (GSZ * NPIX) - mu * mu;
        stats[bg] = make_float2(mu, rsqrtf(var + EPS));
    }
}

// ---------------- K1b: normalize + transpose -> xnT[b][n][c] fp16 ----------------
__global__ void k_norm_t(const float* __restrict__ x, const float* __restrict__ gamma,
                         const float* __restrict__ beta, const float2* __restrict__ stats,
                         f16* __restrict__ xnT) {
    int nt = blockIdx.x, b = blockIdx.y;
    int n0 = nt * 128;
    __shared__ float gS[CH], bS[CH];
    __shared__ float2 stS[GROUPS];
    __shared__ f16 TT[64][136];
    for (int i = threadIdx.x; i < CH; i += 256) { gS[i] = gamma[i]; bS[i] = beta[i]; }
    if (threadIdx.x < GROUPS) stS[threadIdx.x] = stats[b * GROUPS + threadIdx.x];
    __syncthreads();
    for (int cc = 0; cc < CH; cc += 64) {
        __syncthreads();
        for (int i = 0; i < 8; i++) {
            int cid = threadIdx.x + i * 256;
            int c = cid >> 5;
            int n = (cid & 31) * 4;
            int cg = cc + c;
            f32x4 v = *(const f32x4*)(x + ((size_t)(b * CH + cg)) * NPIX + n0 + n);
            float2 st = stS[cg >> 4];
            float g = gS[cg] * st.y;
            float bb = bS[cg] - st.x * g;
            f16x4 h;
            h[0] = (f16)(v.x * g + bb); h[1] = (f16)(v.y * g + bb);
            h[2] = (f16)(v.z * g + bb); h[3] = (f16)(v.w * g + bb);
            *(f16x4*)&TT[c][n] = h;
        }
        __syncthreads();
        for (int i = 0; i < 4; i++) {
            int cid = threadIdx.x + i * 256;
            int n = cid >> 3;
            int k8 = (cid & 7) * 8;
            f16x8 v;
            for (int j = 0; j < 8; j++) v[j] = TT[k8 + j][n];
            *(f16x8*)(xnT + ((size_t)(b * NPIX) + n0 + n) * CH + cc + k8) = v;
        }
    }
}

// ---------------- K2: QKV GEMM (fp16 MFMA), writes qT/kT [b][h][n][d], vN [b][h][d][m] ----------------
__global__ __launch_bounds__(256, 2) void k_qkv(const f16* __restrict__ w16, const float* __restrict__ bias,
                                                const f16* __restrict__ xnT, f16* __restrict__ qT,
                                                f16* __restrict__ kT, f16* __restrict__ vN) {
    int nt = blockIdx.x, ot = blockIdx.y, b = blockIdx.z;
    int n0 = nt * 128, o0 = ot * 128;
    __shared__ union SM {
        struct { f16 A[128][40]; f16 Bt[128][40]; } s;
        f16 Cs[128][136];
    } sm;
    __shared__ float biasS[128];
    if (threadIdx.x < 128) biasS[threadIdx.x] = bias[o0 + threadIdx.x];
    int lane = threadIdx.x & 63, wv = threadIdx.x >> 6;
    int wr = wv >> 1, wc = wv & 1;
    int l15 = lane & 15, quad = lane >> 4;
    f32x4 acc[4][4] = {};
    for (int kk = 0; kk < CH; kk += 32) {
        __syncthreads();
        for (int i = 0; i < 2; i++) {
            int cid = threadIdx.x + i * 256;
            int row = cid >> 2, off = (cid & 3) * 8;
            *(f16x8*)&sm.s.A[row][off]  = *(const f16x8*)(w16 + (size_t)(o0 + row) * CH + kk + off);
            *(f16x8*)&sm.s.Bt[row][off] = *(const f16x8*)(xnT + ((size_t)(b * NPIX) + n0 + row) * CH + kk + off);
        }
        __syncthreads();
        f16x8 af[4], bf[4];
        for (int t = 0; t < 4; t++) {
            af[t] = *(const f16x8*)&sm.s.A[wr * 64 + t * 16 + l15][quad * 8];
            bf[t] = *(const f16x8*)&sm.s.Bt[wc * 64 + t * 16 + l15][quad * 8];
        }
        for (int tm = 0; tm < 4; tm++)
            for (int tn = 0; tn < 4; tn++)
                acc[tm][tn] = __builtin_amdgcn_mfma_f32_16x16x32_f16(af[tm], bf[tn], acc[tm][tn], 0, 0, 0);
    }
    __syncthreads();
    int which = ot >> 2, h = ot & 3;
    for (int tm = 0; tm < 4; tm++)
        for (int tn = 0; tn < 4; tn++)
            for (int r = 0; r < 4; r++) {
                int o = wr * 64 + tm * 16 + quad * 4 + r;
                int n = wc * 64 + tn * 16 + l15;
                float v = acc[tm][tn][r] + biasS[o];
                if (which < 2) sm.Cs[n][o] = (f16)v;
                else           sm.Cs[o][n] = (f16)v;
            }
    __syncthreads();
    f16* dst = (which == 0) ? qT : (which == 1) ? kT : vN;
    for (int i = 0; i < 8; i++) {
        int cid = threadIdx.x + i * 256;
        int row = cid >> 4, off = (cid & 15) * 8;
        f16x8 v = *(f16x8*)&sm.Cs[row][off];
        if (which < 2)
            *(f16x8*)(dst + (((size_t)(b * HEADS + h)) * NPIX + n0 + row) * HD + off) = v;
        else
            *(f16x8*)(dst + (((size_t)(b * HEADS + h)) * HD + row) * NPIX + n0 + off) = v;
    }
}

// ---------------- K3: flash attention v2 ----------------
// LDS: KP [128][128] (swizzled; K-tile, then aliased as P), Vs [128][128] (swizzled) = 64 KB
// -> 2 blocks/CU. Q fragments live in registers (pre-scaled by 1/sqrt(hd)).
// XOR swizzle: 16B block index ^= (row & 7); keeps every b128 access 2-way max.
__global__ __launch_bounds__(256, 2) void k_attn(const f16* __restrict__ qT, const f16* __restrict__ kT,
                                                 const f16* __restrict__ vN, f16* __restrict__ attnT) {
    int nt = blockIdx.x, h = blockIdx.y, b = blockIdx.z;
    int n0 = nt * 128;
    extern __shared__ f16 smem[];
    f16* KP = smem;              // 128*128
    f16* Vs = smem + 128 * 128;  // 128*128
    const f16* qb = qT + ((size_t)(b * HEADS + h)) * NPIX * HD;
    const f16* kb = kT + ((size_t)(b * HEADS + h)) * NPIX * HD;
    const f16* vb = vN + ((size_t)(b * HEADS + h)) * HD * NPIX;
    int tid = threadIdx.x;
    int lane = tid & 63, wv = tid >> 6;
    int l15 = lane & 15, quad = lane >> 4;

    // Q fragments in registers, scale folded in
    f16x8 aq[2][4];
#pragma unroll
    for (int t = 0; t < 2; t++)
#pragma unroll
        for (int dk = 0; dk < 4; dk++) {
            f16x8 v = *(const f16x8*)(qb + (size_t)(n0 + wv * 32 + t * 16 + l15) * HD + dk * 32 + quad * 8);
            aq[t][dk] = v * (f16)0.08838834764831845f;
        }

    float m_i[2][4], l_i[2][4];
#pragma unroll
    for (int t = 0; t < 2; t++)
#pragma unroll
        for (int r = 0; r < 4; r++) { m_i[t][r] = -1e30f; l_i[t][r] = 0.f; }
    f32x4 oacc[2][8] = {};

    for (int mc = 0; mc < 8; mc++) {
        int m0 = mc * 128;
        __syncthreads();  // (A) everyone done with previous P/V reads
#pragma unroll
        for (int i = 0; i < 8; i++) {
            int cid = tid + i * 256;            // 0..2047: (row, 16B-block)
            int row = cid >> 4, blk = cid & 15;
            int sw = ((blk ^ (row & 7)) * 8);
            *(f16x8*)&KP[row * 128 + sw] = *(const f16x8*)(kb + (size_t)(m0 + row) * HD + blk * 8);
            *(f16x8*)&Vs[row * 128 + sw] = *(const f16x8*)(vb + (size_t)row * NPIX + m0 + blk * 8);
        }
        __syncthreads();  // (B) staging visible

        // S = Q K^T for this wave's 32 n-rows x 128 m
        f32x4 sacc[2][8] = {};
#pragma unroll
        for (int dk = 0; dk < 4; dk++) {
            f16x8 bk[8];
#pragma unroll
            for (int t = 0; t < 8; t++) {
                int r = t * 16 + l15;
                bk[t] = *(const f16x8*)&KP[r * 128 + (((4 * dk + quad) ^ (r & 7)) * 8)];
            }
#pragma unroll
            for (int tr = 0; tr < 2; tr++)
#pragma unroll
                for (int tc = 0; tc < 8; tc++)
                    sacc[tr][tc] = __builtin_amdgcn_mfma_f32_16x16x32_f16(aq[tr][dk], bk[tc], sacc[tr][tc], 0, 0, 0);
        }

        // online softmax (scale already folded into Q)
#pragma unroll
        for (int tr = 0; tr < 2; tr++)
#pragma unroll
            for (int r = 0; r < 4; r++) {
                float mx = -1e30f;
#pragma unroll
                for (int tc = 0; tc < 8; tc++) mx = fmaxf(mx, sacc[tr][tc][r]);
                for (int d = 1; d < 16; d <<= 1) mx = fmaxf(mx, __shfl_xor(mx, d, 16));
                float mnew = fmaxf(m_i[tr][r], mx);
                float alpha = __expf(m_i[tr][r] - mnew);
                m_i[tr][r] = mnew;
                float rs = 0.f;
#pragma unroll
                for (int tc = 0; tc < 8; tc++) {
                    float p = __expf(sacc[tr][tc][r] - mnew);
                    sacc[tr][tc][r] = p;
                    rs += p;
                }
                for (int d = 1; d < 16; d <<= 1) rs += __shfl_xor(rs, d, 16);
                l_i[tr][r] = l_i[tr][r] * alpha + rs;
#pragma unroll
                for (int tc = 0; tc < 8; tc++) oacc[tr][tc][r] *= alpha;
            }

        __syncthreads();  // (C) all waves finished reading K-tile; safe to overwrite with P

        // write P (own 32 rows) into KP, swizzled
#pragma unroll
        for (int tr = 0; tr < 2; tr++)
#pragma unroll
            for (int r = 0; r < 4; r++) {
                int n = wv * 32 + tr * 16 + quad * 4 + r;
#pragma unroll
                for (int tc = 0; tc < 8; tc++) {
                    int col = tc * 16 + l15;
                    KP[n * 128 + (((col >> 3) ^ (n & 7)) * 8) + (col & 7)] = (f16)sacc[tr][tc][r];
                }
            }

        // O += P V^T (own P rows; all V rows)
#pragma unroll
        for (int mk = 0; mk < 4; mk++) {
            f16x8 ap[2], bv[8];
#pragma unroll
            for (int t = 0; t < 2; t++) {
                int rr = wv * 32 + t * 16 + l15;
                ap[t] = *(const f16x8*)&KP[rr * 128 + (((4 * mk + quad) ^ (rr & 7)) * 8)];
            }
#pragma unroll
            for (int t = 0; t < 8; t++) {
                int rd = t * 16 + l15;
                bv[t] = *(const f16x8*)&Vs[rd * 128 + (((4 * mk + quad) ^ (rd & 7)) * 8)];
            }
#pragma unroll
            for (int tr = 0; tr < 2; tr++)
#pragma unroll
                for (int tc = 0; tc < 8; tc++)
                    oacc[tr][tc] = __builtin_amdgcn_mfma_f32_16x16x32_f16(ap[tr], bv[tc], oacc[tr][tc], 0, 0, 0);
        }
    }

    // epilogue: O/l -> KP (own rows, swizzled) -> coalesced global [n][c]
#pragma unroll
    for (int tr = 0; tr < 2; tr++)
#pragma unroll
        for (int r = 0; r < 4; r++) {
            float inv = 1.f / l_i[tr][r];
            int n = wv * 32 + tr * 16 + quad * 4 + r;
#pragma unroll
            for (int tc = 0; tc < 8; tc++) {
                int col = tc * 16 + l15;
                KP[n * 128 + (((col >> 3) ^ (n & 7)) * 8) + (col & 7)] = (f16)(oacc[tr][tc][r] * inv);
            }
        }
    __syncthreads();
#pragma unroll
    for (int i = 0; i < 8; i++) {
        int cid = tid + i * 256;
        int row = cid >> 4, blk = cid & 15;
        f16x8 v = *(f16x8*)&KP[row * 128 + ((blk ^ (row & 7)) * 8)];
        *(f16x8*)(attnT + ((size_t)(b * NPIX) + n0 + row) * CH + h * HD + blk * 8) = v;
    }
}

// ---------------- K4: proj GEMM + bias + residual -> fp32 out ----------------
__global__ __launch_bounds__(256, 2) void k_proj(const f16* __restrict__ w16, const float* __restrict__ bias,
                                                 const f16* __restrict__ attnT, const float* __restrict__ x,
                                                 float* __restrict__ out) {
    int nt = blockIdx.x, ot = blockIdx.y, b = blockIdx.z;
    int n0 = nt * 128, o0 = ot * 128;
    __shared__ union SM {
        struct { f16 A[128][40]; f16 Bt[128][40]; } s;
        f16 Cs[128][136];
    } sm;
    __shared__ float biasS[128];
    if (threadIdx.x < 128) biasS[threadIdx.x] = bias[o0 + threadIdx.x];
    int lane = threadIdx.x & 63, wv = threadIdx.x >> 6;
    int wr = wv >> 1, wc = wv & 1;
    int l15 = lane & 15, quad = lane >> 4;
    f32x4 acc[4][4] = {};
    for (int kk = 0; kk < CH; kk += 32) {
        __syncthreads();
        for (int i = 0; i < 2; i++) {
            int cid = threadIdx.x + i * 256;
            int row = cid >> 2, off = (cid & 3) * 8;
            *(f16x8*)&sm.s.A[row][off]  = *(const f16x8*)(w16 + (size_t)(o0 + row) * CH + kk + off);
            *(f16x8*)&sm.s.Bt[row][off] = *(const f16x8*)(attnT + ((size_t)(b * NPIX) + n0 + row) * CH + kk + off);
        }
        __syncthreads();
        f16x8 af[4], bf[4];
        for (int t = 0; t < 4; t++) {
            af[t] = *(const f16x8*)&sm.s.A[wr * 64 + t * 16 + l15][quad * 8];
            bf[t] = *(const f16x8*)&sm.s.Bt[wc * 64 + t * 16 + l15][quad * 8];
        }
        for (int tm = 0; tm < 4; tm++)
            for (int tn = 0; tn < 4; tn++)
                acc[tm][tn] = __builtin_amdgcn_mfma_f32_16x16x32_f16(af[tm], bf[tn], acc[tm][tn], 0, 0, 0);
    }
    __syncthreads();
    for (int tm = 0; tm < 4; tm++)
        for (int tn = 0; tn < 4; tn++)
            for (int r = 0; r < 4; r++) {
                int o = wr * 64 + tm * 16 + quad * 4 + r;
                int n = wc * 64 + tn * 16 + l15;
                sm.Cs[o][n] = (f16)(acc[tm][tn][r] + biasS[o]);
            }
    __syncthreads();
    for (int i = 0; i < 8; i++) {
        int cid = threadIdx.x + i * 256;
        int row = cid >> 4, off = (cid & 15) * 8;
        f16x8 v = *(f16x8*)&sm.Cs[row][off];
        size_t gofs = ((size_t)(b * CH) + o0 + row) * NPIX + n0 + off;
        const float* xp = x + gofs;
        float* op = out + gofs;
        f32x4 o0v, o1v;
        o0v.x = xp[0] + (float)v[0]; o0v.y = xp[1] + (float)v[1];
        o0v.z = xp[2] + (float)v[2]; o0v.w = xp[3] + (float)v[3];
        o1v.x = xp[4] + (float)v[4]; o1v.y = xp[5] + (float)v[5];
        o1v.z = xp[6] + (float)v[6]; o1v.w = xp[7] + (float)v[7];
        *(f32x4*)op = o0v; *(f32x4*)(op + 4) = o1v;
    }
}

extern "C" void kernel_launch(void* const* d_in, const int* in_sizes, int n_in,
                              void* d_out, int out_size, void* d_ws, size_t ws_size,
                              hipStream_t stream) {
    const float* x     = (const float*)d_in[0];
    const float* gamma = (const float*)d_in[1];
    const float* beta  = (const float*)d_in[2];
    const float* wqkv  = (const float*)d_in[3];
    const float* bqkv  = (const float*)d_in[4];
    const float* wproj = (const float*)d_in[5];
    const float* bproj = (const float*)d_in[6];
    float* out = (float*)d_out;

    char* p = (char*)d_ws;
    float2* stats = (float2*)p;          p += 16 * 32 * sizeof(float2);
    f16* wq16 = (f16*)p;                 p += (size_t)3 * CH * CH * 2;
    f16* wp16 = (f16*)p;                 p += (size_t)CH * CH * 2;
    f16* xnT  = (f16*)p;                 p += (size_t)BATCH * NPIX * CH * 2;
    f16* qT   = (f16*)p;                 p += (size_t)BATCH * HEADS * NPIX * HD * 2;
    f16* kT   = (f16*)p;                 p += (size_t)BATCH * HEADS * NPIX * HD * 2;
    f16* vN   = (f16*)p;                 p += (size_t)BATCH * HEADS * HD * NPIX * 2;
    f16* attnT = (f16*)p;                p += (size_t)BATCH * NPIX * CH * 2;

    k_convert<<<dim3((3 * CH * CH + 255) / 256), 256, 0, stream>>>(wqkv, wproj, wq16, wp16);
    k_stats<<<dim3(BATCH * GROUPS), 256, 0, stream>>>(x, stats);
    k_norm_t<<<dim3(8, BATCH), 256, 0, stream>>>(x, gamma, beta, stats, xnT);
    k_qkv<<<dim3(8, 12, BATCH), 256, 0, stream>>>(wq16, bqkv, xnT, qT, kT, vN);

    hipFuncSetAttribute((const void*)k_attn, hipFuncAttributeMaxDynamicSharedMemorySize, 2 * 128 * 128 * 2);
    k_attn<<<dim3(8, HEADS, BATCH), 256, 2 * 128 * 128 * 2, stream>>>(qT, kT, vN, attnT);

    k_proj<<<dim3(8, 4, BATCH), 256, 0, stream>>>(wp16, bproj, attnT, x, out);
}

// Round 3
// 359.968 us; speedup vs baseline: 1.1968x; 1.1968x over previous
//
#include <hip/hip_runtime.h>

#define CH 512
#define HEADS 4
#define HD 128
#define NPIX 1024
#define BATCH 16
#define GROUPS 32
#define GSZ 16
#define EPS 1e-5f

typedef _Float16 f16;
typedef _Float16 f16x8 __attribute__((ext_vector_type(8)));
typedef _Float16 f16x4 __attribute__((ext_vector_type(4)));
typedef float f32x4 __attribute__((ext_vector_type(4)));

// async global->LDS copy, 16B per lane per instruction.
// LDS dest must be wave-uniform base; HW adds lane*16.
__device__ __forceinline__ void gld16(const f16* g, f16* l) {
    __builtin_amdgcn_global_load_lds((__attribute__((address_space(1))) const void*)g,
                                     (__attribute__((address_space(3))) void*)l, 16, 0, 0);
}

// ---------------- K0: convert + pre-transpose weights ----------------
// wqT layout: [ot(12)][kblk(64)][o_local(128)][8]  (16B chunk = 8 f16 along k)
// wpT layout: [ot(4)][kblk(64)][o_local(128)][8]
__global__ void k_convert(const float* __restrict__ wq, const float* __restrict__ wp,
                          f16* __restrict__ wqT, f16* __restrict__ wpT) {
    int c = blockIdx.x * 256 + threadIdx.x;   // chunk index
    {   // wq: 3*512*512/8 = 98304 chunks
        int ot = c >> 13, kbl = (c >> 7) & 63, ol = c & 127;
        const float* s = wq + ((size_t)(ot * 128 + ol)) * CH + kbl * 8;
        f32x4 a = *(const f32x4*)s, b = *(const f32x4*)(s + 4);
        f16x8 v;
        v[0] = (f16)a.x; v[1] = (f16)a.y; v[2] = (f16)a.z; v[3] = (f16)a.w;
        v[4] = (f16)b.x; v[5] = (f16)b.y; v[6] = (f16)b.z; v[7] = (f16)b.w;
        *(f16x8*)(wqT + (size_t)c * 8) = v;
    }
    if (c < 32768) {  // wp: 512*512/8 chunks
        int ot = c >> 13, kbl = (c >> 7) & 63, ol = c & 127;
        const float* s = wp + ((size_t)(ot * 128 + ol)) * CH + kbl * 8;
        f32x4 a = *(const f32x4*)s, b = *(const f32x4*)(s + 4);
        f16x8 v;
        v[0] = (f16)a.x; v[1] = (f16)a.y; v[2] = (f16)a.z; v[3] = (f16)a.w;
        v[4] = (f16)b.x; v[5] = (f16)b.y; v[6] = (f16)b.z; v[7] = (f16)b.w;
        *(f16x8*)(wpT + (size_t)c * 8) = v;
    }
}

// ---------------- K1a: groupnorm stats ----------------
__global__ void k_stats(const float* __restrict__ x, float2* __restrict__ stats) {
    int bg = blockIdx.x;
    const f32x4* b4 = (const f32x4*)(x + (size_t)bg * (GSZ * NPIX));
    float s = 0.f, ss = 0.f;
    for (int i = threadIdx.x; i < GSZ * NPIX / 4; i += 256) {
        f32x4 v = b4[i];
        s  += v.x + v.y + v.z + v.w;
        ss += v.x * v.x + v.y * v.y + v.z * v.z + v.w * v.w;
    }
    for (int off = 32; off; off >>= 1) { s += __shfl_down(s, off); ss += __shfl_down(ss, off); }
    __shared__ float as_[4], ass[4];
    int wv = threadIdx.x >> 6, ln = threadIdx.x & 63;
    if (ln == 0) { as_[wv] = s; ass[wv] = ss; }
    __syncthreads();
    if (threadIdx.x == 0) {
        float S = as_[0] + as_[1] + as_[2] + as_[3];
        float SS = ass[0] + ass[1] + ass[2] + ass[3];
        float mu = S / (GSZ * NPIX);
        float var = SS / (GSZ * NPIX) - mu * mu;
        stats[bg] = make_float2(mu, rsqrtf(var + EPS));
    }
}

// ---------------- K1b: normalize + transpose -> xnT tiled ----------------
// xnT layout per (b,nt): [cblk(64)][n(128)][8]; tile = 65536 f16
__global__ void k_norm_t(const float* __restrict__ x, const float* __restrict__ gamma,
                         const float* __restrict__ beta, const float2* __restrict__ stats,
                         f16* __restrict__ xnT) {
    int nt = blockIdx.x, b = blockIdx.y;
    int n0 = nt * 128;
    __shared__ float gS[CH], bS[CH];
    __shared__ float2 stS[GROUPS];
    __shared__ f16 TT[64][136];
    for (int i = threadIdx.x; i < CH; i += 256) { gS[i] = gamma[i]; bS[i] = beta[i]; }
    if (threadIdx.x < GROUPS) stS[threadIdx.x] = stats[b * GROUPS + threadIdx.x];
    __syncthreads();
    f16* tb = xnT + ((size_t)(b * 8 + nt)) * 65536;
    for (int cc = 0; cc < CH; cc += 64) {
        __syncthreads();
        for (int i = 0; i < 8; i++) {
            int cid = threadIdx.x + i * 256;
            int c = cid >> 5;
            int n = (cid & 31) * 4;
            int cg = cc + c;
            f32x4 v = *(const f32x4*)(x + ((size_t)(b * CH + cg)) * NPIX + n0 + n);
            float2 st = stS[cg >> 4];
            float g = gS[cg] * st.y;
            float bb = bS[cg] - st.x * g;
            f16x4 h;
            h[0] = (f16)(v.x * g + bb); h[1] = (f16)(v.y * g + bb);
            h[2] = (f16)(v.z * g + bb); h[3] = (f16)(v.w * g + bb);
            *(f16x4*)&TT[c][n] = h;
        }
        __syncthreads();
        for (int i = 0; i < 4; i++) {
            int cid = threadIdx.x + i * 256;
            int cbl = cid >> 7, n = cid & 127;
            f16x8 v;
            for (int j = 0; j < 8; j++) v[j] = TT[cbl * 8 + j][n];
            *(f16x8*)(tb + (size_t)((cc >> 3) + cbl) * 1024 + n * 8) = v;
        }
    }
}

// ---------------- K2: QKV GEMM, BK=64, async staging, tiled outputs ----------------
// qF per (b,h,nt): fragment-linear: addr = seg*512 + lane*8 + j,
//   seg=((n>>5)*2+((n>>4)&1))*4+(d>>5), lane=((d>>3)&3)*16+(n&15), j=d&7
// kTl per (b,h,mt): [dblk(16)][m(128)][8]
// vTl per (b,h,mt): [mblk(16)][c(128)][8]
__global__ __launch_bounds__(256, 2) void k_qkv(const f16* __restrict__ wT, const float* __restrict__ bias,
                                                const f16* __restrict__ xnT, f16* __restrict__ qF,
                                                f16* __restrict__ kTl, f16* __restrict__ vTl) {
    int nt = blockIdx.x, ot = blockIdx.y, b = blockIdx.z;
    int o0 = ot * 128;
    __shared__ union SM {
        struct { f16 As[8192]; f16 Bs[8192]; } s;   // [kbl(8)][row(128)][8] each
        f16 Cf[16384];
    } sm;
    __shared__ float biasS[128];
    if (threadIdx.x < 128) biasS[threadIdx.x] = bias[o0 + threadIdx.x];
    int tid = threadIdx.x, lane = tid & 63, wv = tid >> 6;
    int wr = wv >> 1, wc = wv & 1;
    int l15 = lane & 15, quad = lane >> 4;
    const f16* wA = wT + (size_t)ot * 65536;
    const f16* xB = xnT + ((size_t)(b * 8 + nt)) * 65536;
    f32x4 acc[4][4] = {};
    for (int kk = 0; kk < CH; kk += 64) {
        __syncthreads();
        const f16* sa = wA + (size_t)(kk >> 3) * 1024;
        const f16* sb = xB + (size_t)(kk >> 3) * 1024;
#pragma unroll
        for (int i = 0; i < 4; i++) {
            int s = wv * 4 + i;                 // 0..15, 64 chunks each
            gld16(sa + (size_t)(s * 64 + lane) * 8, sm.s.As + s * 512);
            gld16(sb + (size_t)(s * 64 + lane) * 8, sm.s.Bs + s * 512);
        }
        __syncthreads();
#pragma unroll
        for (int dk = 0; dk < 2; dk++) {
            f16x8 af[4], bf[4];
#pragma unroll
            for (int t = 0; t < 4; t++) {
                af[t] = *(const f16x8*)(sm.s.As + (dk * 4 + quad) * 1024 + (wr * 64 + t * 16 + l15) * 8);
                bf[t] = *(const f16x8*)(sm.s.Bs + (dk * 4 + quad) * 1024 + (wc * 64 + t * 16 + l15) * 8);
            }
#pragma unroll
            for (int tm = 0; tm < 4; tm++)
#pragma unroll
                for (int tn = 0; tn < 4; tn++)
                    acc[tm][tn] = __builtin_amdgcn_mfma_f32_16x16x32_f16(af[tm], bf[tn], acc[tm][tn], 0, 0, 0);
        }
    }
    __syncthreads();
    int which = ot >> 2, h = ot & 3;
    // scatter acc -> Cf in the consumer's tile layout
#pragma unroll
    for (int tm = 0; tm < 4; tm++)
#pragma unroll
        for (int tn = 0; tn < 4; tn++)
#pragma unroll
            for (int r = 0; r < 4; r++) {
                int o = wr * 64 + tm * 16 + quad * 4 + r;   // output channel (d or c)
                int n = wc * 64 + tn * 16 + l15;            // pixel
                f16 v = (f16)(acc[tm][tn][r] + biasS[o]);
                int addr;
                if (which == 0)
                    addr = (((n >> 5) * 2 + ((n >> 4) & 1)) * 4 + (o >> 5)) * 512
                         + ((o >> 3) & 3) * 128 + (n & 15) * 8 + (o & 7);
                else if (which == 1)
                    addr = (o >> 3) * 1024 + n * 8 + (o & 7);
                else
                    addr = (n >> 3) * 1024 + o * 8 + (n & 7);
                sm.Cf[addr] = v;
            }
    __syncthreads();
    f16* tb = (which == 0) ? (qF + ((size_t)((b * 4 + h) * 8 + nt)) * 16384)
            : (which == 1) ? (kTl + ((size_t)((b * 4 + h) * 8 + nt)) * 16384)
                           : (vTl + ((size_t)((b * 4 + h) * 8 + nt)) * 16384);
#pragma unroll
    for (int i = 0; i < 8; i++) {
        int cid = tid + i * 256;
        *(f16x8*)(tb + (size_t)cid * 8) = *(const f16x8*)(sm.Cf + cid * 8);
    }
}

// ---------------- K3: flash attention v3 (async staging, tiled IO) ----------------
// LDS: KP (16384 f16: K [dblk][m], then P row-major-swizzled, then O) + Vl (16384) = 64 KB
__global__ __launch_bounds__(256, 2) void k_attn(const f16* __restrict__ qF, const f16* __restrict__ kTl,
                                                 const f16* __restrict__ vTl, f16* __restrict__ oT) {
    int bid = blockIdx.x;
    int nt = bid >> 6, group = bid & 63;      // group=(b,h) -> same XCD for all 8 nt
    int b = group >> 2, h = group & 3;
    extern __shared__ f16 smem[];
    f16* KP = smem;
    f16* Vl = smem + 16384;
    const f16* qb = qF + ((size_t)(group * 8 + nt)) * 16384;
    const f16* kb = kTl + (size_t)group * 8 * 16384;
    const f16* vb = vTl + (size_t)group * 8 * 16384;
    int tid = threadIdx.x, lane = tid & 63, wv = tid >> 6;
    int l15 = lane & 15, quad = lane >> 4;

    // Q fragments: fully coalesced 16B/lane, scale folded in
    f16x8 aq[2][4];
#pragma unroll
    for (int t = 0; t < 2; t++)
#pragma unroll
        for (int dk = 0; dk < 4; dk++) {
            int seg = (wv * 2 + t) * 4 + dk;
            f16x8 v = *(const f16x8*)(qb + seg * 512 + lane * 8);
            aq[t][dk] = v * (f16)0.08838834764831845f;
        }

    float m_i[2][4], l_i[2][4];
#pragma unroll
    for (int t = 0; t < 2; t++)
#pragma unroll
        for (int r = 0; r < 4; r++) { m_i[t][r] = -1e30f; l_i[t][r] = 0.f; }
    f32x4 oacc[2][8] = {};

    for (int mc = 0; mc < 8; mc++) {
        __syncthreads();  // (A) prev P/V reads done
        const f16* ks = kb + (size_t)mc * 16384;
        const f16* vs = vb + (size_t)mc * 16384;
#pragma unroll
        for (int i = 0; i < 8; i++) {
            int s = wv * 8 + i;               // 0..31
            gld16(ks + (size_t)(s * 64 + lane) * 8, KP + s * 512);
            gld16(vs + (size_t)(s * 64 + lane) * 8, Vl + s * 512);
        }
        __syncthreads();  // (B) staged

        // S = Q K^T : K from [dblk][m] layout
        f32x4 sacc[2][8] = {};
#pragma unroll
        for (int dk = 0; dk < 4; dk++) {
            f16x8 bk[8];
#pragma unroll
            for (int t = 0; t < 8; t++)
                bk[t] = *(const f16x8*)(KP + (dk * 4 + quad) * 1024 + (t * 16 + l15) * 8);
#pragma unroll
            for (int tr = 0; tr < 2; tr++)
#pragma unroll
                for (int tc = 0; tc < 8; tc++)
                    sacc[tr][tc] = __builtin_amdgcn_mfma_f32_16x16x32_f16(aq[tr][dk], bk[tc], sacc[tr][tc], 0, 0, 0);
        }

        // online softmax
#pragma unroll
        for (int tr = 0; tr < 2; tr++)
#pragma unroll
            for (int r = 0; r < 4; r++) {
                float mx = -1e30f;
#pragma unroll
                for (int tc = 0; tc < 8; tc++) mx = fmaxf(mx, sacc[tr][tc][r]);
                for (int d = 1; d < 16; d <<= 1) mx = fmaxf(mx, __shfl_xor(mx, d, 16));
                float mnew = fmaxf(m_i[tr][r], mx);
                float alpha = __expf(m_i[tr][r] - mnew);
                m_i[tr][r] = mnew;
                float rs = 0.f;
#pragma unroll
                for (int tc = 0; tc < 8; tc++) {
                    float p = __expf(sacc[tr][tc][r] - mnew);
                    sacc[tr][tc][r] = p;
                    rs += p;
                }
                for (int d = 1; d < 16; d <<= 1) rs += __shfl_xor(rs, d, 16);
                l_i[tr][r] = l_i[tr][r] * alpha + rs;
#pragma unroll
                for (int tc = 0; tc < 8; tc++) oacc[tr][tc][r] *= alpha;
            }

        __syncthreads();  // (C) all K reads done; safe to overwrite with P

        // P -> KP, row-major + xor swizzle (own rows only)
#pragma unroll
        for (int tr = 0; tr < 2; tr++)
#pragma unroll
            for (int r = 0; r < 4; r++) {
                int n = wv * 32 + tr * 16 + quad * 4 + r;
#pragma unroll
                for (int tc = 0; tc < 8; tc++) {
                    int col = tc * 16 + l15;
                    KP[n * 128 + (((col >> 3) ^ (n & 7)) * 8) + (col & 7)] = (f16)sacc[tr][tc][r];
                }
            }

        // O += P V^T : V from [mblk][c] layout
#pragma unroll
        for (int mk = 0; mk < 4; mk++) {
            f16x8 ap[2], bv[8];
#pragma unroll
            for (int t = 0; t < 2; t++) {
                int rr = wv * 32 + t * 16 + l15;
                ap[t] = *(const f16x8*)(KP + rr * 128 + (((4 * mk + quad) ^ (rr & 7)) * 8));
            }
#pragma unroll
            for (int t = 0; t < 8; t++)
                bv[t] = *(const f16x8*)(Vl + (mk * 4 + quad) * 1024 + (t * 16 + l15) * 8);
#pragma unroll
            for (int tr = 0; tr < 2; tr++)
#pragma unroll
                for (int tc = 0; tc < 8; tc++)
                    oacc[tr][tc] = __builtin_amdgcn_mfma_f32_16x16x32_f16(ap[tr], bv[tc], oacc[tr][tc], 0, 0, 0);
        }
    }

    // epilogue: O/l -> KP (row-major swizzled, own rows) -> tiled global [cblk][n]
#pragma unroll
    for (int tr = 0; tr < 2; tr++)
#pragma unroll
        for (int r = 0; r < 4; r++) {
            float inv = 1.f / l_i[tr][r];
            int n = wv * 32 + tr * 16 + quad * 4 + r;
#pragma unroll
            for (int tc = 0; tc < 8; tc++) {
                int col = tc * 16 + l15;
                KP[n * 128 + (((col >> 3) ^ (n & 7)) * 8) + (col & 7)] = (f16)(oacc[tr][tc][r] * inv);
            }
        }
    __syncthreads();
    f16* ob = oT + ((size_t)(b * 8 + nt)) * 65536;   // [cblk(64)][n][8]; this head: cblks h*16..
#pragma unroll
    for (int i = 0; i < 8; i++) {
        int cid = tid + i * 256;                     // 0..2047
        int cbl = cid >> 7, n = cid & 127;
        f16x8 v = *(const f16x8*)(KP + n * 128 + ((cbl ^ (n & 7)) * 8));
        *(f16x8*)(ob + (size_t)(h * 16 + cbl) * 1024 + n * 8) = v;
    }
}

// ---------------- K4: proj GEMM + bias + residual -> fp32 out ----------------
__global__ __launch_bounds__(256, 2) void k_proj(const f16* __restrict__ wT, const float* __restrict__ bias,
                                                 const f16* __restrict__ oT, const float* __restrict__ x,
                                                 float* __restrict__ out) {
    int nt = blockIdx.x, ot = blockIdx.y, b = blockIdx.z;
    int n0 = nt * 128, o0 = ot * 128;
    __shared__ union SM {
        struct { f16 As[8192]; f16 Bs[8192]; } s;
        f16 Cs[128][136];
    } sm;
    __shared__ float biasS[128];
    if (threadIdx.x < 128) biasS[threadIdx.x] = bias[o0 + threadIdx.x];
    int tid = threadIdx.x, lane = tid & 63, wv = tid >> 6;
    int wr = wv >> 1, wc = wv & 1;
    int l15 = lane & 15, quad = lane >> 4;
    const f16* wA = wT + (size_t)ot * 65536;
    const f16* xB = oT + ((size_t)(b * 8 + nt)) * 65536;
    f32x4 acc[4][4] = {};
    for (int kk = 0; kk < CH; kk += 64) {
        __syncthreads();
        const f16* sa = wA + (size_t)(kk >> 3) * 1024;
        const f16* sb = xB + (size_t)(kk >> 3) * 1024;
#pragma unroll
        for (int i = 0; i < 4; i++) {
            int s = wv * 4 + i;
            gld16(sa + (size_t)(s * 64 + lane) * 8, sm.s.As + s * 512);
            gld16(sb + (size_t)(s * 64 + lane) * 8, sm.s.Bs + s * 512);
        }
        __syncthreads();
#pragma unroll
        for (int dk = 0; dk < 2; dk++) {
            f16x8 af[4], bf[4];
#pragma unroll
            for (int t = 0; t < 4; t++) {
                af[t] = *(const f16x8*)(sm.s.As + (dk * 4 + quad) * 1024 + (wr * 64 + t * 16 + l15) * 8);
                bf[t] = *(const f16x8*)(sm.s.Bs + (dk * 4 + quad) * 1024 + (wc * 64 + t * 16 + l15) * 8);
            }
#pragma unroll
            for (int tm = 0; tm < 4; tm++)
#pragma unroll
                for (int tn = 0; tn < 4; tn++)
                    acc[tm][tn] = __builtin_amdgcn_mfma_f32_16x16x32_f16(af[tm], bf[tn], acc[tm][tn], 0, 0, 0);
        }
    }
    __syncthreads();
#pragma unroll
    for (int tm = 0; tm < 4; tm++)
#pragma unroll
        for (int tn = 0; tn < 4; tn++)
#pragma unroll
            for (int r = 0; r < 4; r++) {
                int o = wr * 64 + tm * 16 + quad * 4 + r;
                int n = wc * 64 + tn * 16 + l15;
                sm.Cs[o][n] = (f16)(acc[tm][tn][r] + biasS[o]);
            }
    __syncthreads();
#pragma unroll
    for (int i = 0; i < 8; i++) {
        int cid = tid + i * 256;
        int row = cid >> 4, off = (cid & 15) * 8;
        f16x8 v = *(const f16x8*)&sm.Cs[row][off];
        size_t gofs = ((size_t)(b * CH) + o0 + row) * NPIX + n0 + off;
        const float* xp = x + gofs;
        float* op = out + gofs;
        f32x4 o0v, o1v;
        o0v.x = xp[0] + (float)v[0]; o0v.y = xp[1] + (float)v[1];
        o0v.z = xp[2] + (float)v[2]; o0v.w = xp[3] + (float)v[3];
        o1v.x = xp[4] + (float)v[4]; o1v.y = xp[5] + (float)v[5];
        o1v.z = xp[6] + (float)v[6]; o1v.w = xp[7] + (float)v[7];
        *(f32x4*)op = o0v; *(f32x4*)(op + 4) = o1v;
    }
}

extern "C" void kernel_launch(void* const* d_in, const int* in_sizes, int n_in,
                              void* d_out, int out_size, void* d_ws, size_t ws_size,
                              hipStream_t stream) {
    const float* x     = (const float*)d_in[0];
    const float* gamma = (const float*)d_in[1];
    const float* beta  = (const float*)d_in[2];
    const float* wqkv  = (const float*)d_in[3];
    const float* bqkv  = (const float*)d_in[4];
    const float* wproj = (const float*)d_in[5];
    const float* bproj = (const float*)d_in[6];
    float* out = (float*)d_out;

    char* p = (char*)d_ws;
    float2* stats = (float2*)p;   p += 16 * 32 * sizeof(float2);
    f16* wqT = (f16*)p;           p += (size_t)3 * CH * CH * 2;
    f16* wpT = (f16*)p;           p += (size_t)CH * CH * 2;
    f16* xnT = (f16*)p;           p += (size_t)BATCH * NPIX * CH * 2;
    f16* qF  = (f16*)p;           p += (size_t)BATCH * HEADS * NPIX * HD * 2;
    f16* kTl = (f16*)p;           p += (size_t)BATCH * HEADS * NPIX * HD * 2;
    f16* vTl = (f16*)p;           p += (size_t)BATCH * HEADS * NPIX * HD * 2;
    f16* oT  = (f16*)p;           p += (size_t)BATCH * NPIX * CH * 2;

    k_convert<<<dim3(384), 256, 0, stream>>>(wqkv, wproj, wqT, wpT);
    k_stats<<<dim3(BATCH * GROUPS), 256, 0, stream>>>(x, stats);
    k_norm_t<<<dim3(8, BATCH), 256, 0, stream>>>(x, gamma, beta, stats, xnT);
    k_qkv<<<dim3(8, 12, BATCH), 256, 0, stream>>>(wqT, bqkv, xnT, qF, kTl, vTl);

    hipFuncSetAttribute((const void*)k_attn, hipFuncAttributeMaxDynamicSharedMemorySize, 65536);
    k_attn<<<dim3(512), 256, 65536, stream>>>(qF, kTl, vTl, oT);

    k_proj<<<dim3(8, 4, BATCH), 256, 0, stream>>>(wpT, bproj, oT, x, out);
}

// Round 4
// 308.304 us; speedup vs baseline: 1.3973x; 1.1676x over previous
//
#include <hip/hip_runtime.h>

#define CH 512
#define HEADS 4
#define HD 128
#define NPIX 1024
#define BATCH 16
#define GROUPS 32
#define GSZ 16
#define EPS 1e-5f

typedef _Float16 f16;
typedef _Float16 f16x8 __attribute__((ext_vector_type(8)));
typedef _Float16 f16x4 __attribute__((ext_vector_type(4)));
typedef float f32x4 __attribute__((ext_vector_type(4)));

__device__ __forceinline__ void gld16(const f16* g, f16* l) {
    __builtin_amdgcn_global_load_lds((__attribute__((address_space(1))) const void*)g,
                                     (__attribute__((address_space(3))) void*)l, 16, 0, 0);
}

// ---------------- K0: convert + pre-transpose weights ----------------
__global__ void k_convert(const float* __restrict__ wq, const float* __restrict__ wp,
                          f16* __restrict__ wqT, f16* __restrict__ wpT) {
    int c = blockIdx.x * 256 + threadIdx.x;
    {
        int ot = c >> 13, kbl = (c >> 7) & 63, ol = c & 127;
        const float* s = wq + ((size_t)(ot * 128 + ol)) * CH + kbl * 8;
        f32x4 a = *(const f32x4*)s, b = *(const f32x4*)(s + 4);
        f16x8 v;
        v[0] = (f16)a.x; v[1] = (f16)a.y; v[2] = (f16)a.z; v[3] = (f16)a.w;
        v[4] = (f16)b.x; v[5] = (f16)b.y; v[6] = (f16)b.z; v[7] = (f16)b.w;
        *(f16x8*)(wqT + (size_t)c * 8) = v;
    }
    if (c < 32768) {
        int ot = c >> 13, kbl = (c >> 7) & 63, ol = c & 127;
        const float* s = wp + ((size_t)(ot * 128 + ol)) * CH + kbl * 8;
        f32x4 a = *(const f32x4*)s, b = *(const f32x4*)(s + 4);
        f16x8 v;
        v[0] = (f16)a.x; v[1] = (f16)a.y; v[2] = (f16)a.z; v[3] = (f16)a.w;
        v[4] = (f16)b.x; v[5] = (f16)b.y; v[6] = (f16)b.z; v[7] = (f16)b.w;
        *(f16x8*)(wpT + (size_t)c * 8) = v;
    }
}

// ---------------- K1a: groupnorm stats ----------------
__global__ void k_stats(const float* __restrict__ x, float2* __restrict__ stats) {
    int bg = blockIdx.x;
    const f32x4* b4 = (const f32x4*)(x + (size_t)bg * (GSZ * NPIX));
    float s = 0.f, ss = 0.f;
    for (int i = threadIdx.x; i < GSZ * NPIX / 4; i += 256) {
        f32x4 v = b4[i];
        s  += v.x + v.y + v.z + v.w;
        ss += v.x * v.x + v.y * v.y + v.z * v.z + v.w * v.w;
    }
    for (int off = 32; off; off >>= 1) { s += __shfl_down(s, off); ss += __shfl_down(ss, off); }
    __shared__ float as_[4], ass[4];
    int wv = threadIdx.x >> 6, ln = threadIdx.x & 63;
    if (ln == 0) { as_[wv] = s; ass[wv] = ss; }
    __syncthreads();
    if (threadIdx.x == 0) {
        float S = as_[0] + as_[1] + as_[2] + as_[3];
        float SS = ass[0] + ass[1] + ass[2] + ass[3];
        float mu = S / (GSZ * NPIX);
        float var = SS / (GSZ * NPIX) - mu * mu;
        stats[bg] = make_float2(mu, rsqrtf(var + EPS));
    }
}

// ---------------- K1b: normalize + transpose -> xnT tiled ----------------
__global__ void k_norm_t(const float* __restrict__ x, const float* __restrict__ gamma,
                         const float* __restrict__ beta, const float2* __restrict__ stats,
                         f16* __restrict__ xnT) {
    int nt = blockIdx.x, b = blockIdx.y;
    int n0 = nt * 128;
    __shared__ float gS[CH], bS[CH];
    __shared__ float2 stS[GROUPS];
    __shared__ f16 TT[64][136];
    for (int i = threadIdx.x; i < CH; i += 256) { gS[i] = gamma[i]; bS[i] = beta[i]; }
    if (threadIdx.x < GROUPS) stS[threadIdx.x] = stats[b * GROUPS + threadIdx.x];
    __syncthreads();
    f16* tb = xnT + ((size_t)(b * 8 + nt)) * 65536;
    for (int cc = 0; cc < CH; cc += 64) {
        __syncthreads();
        for (int i = 0; i < 8; i++) {
            int cid = threadIdx.x + i * 256;
            int c = cid >> 5;
            int n = (cid & 31) * 4;
            int cg = cc + c;
            f32x4 v = *(const f32x4*)(x + ((size_t)(b * CH + cg)) * NPIX + n0 + n);
            float2 st = stS[cg >> 4];
            float g = gS[cg] * st.y;
            float bb = bS[cg] - st.x * g;
            f16x4 h;
            h[0] = (f16)(v.x * g + bb); h[1] = (f16)(v.y * g + bb);
            h[2] = (f16)(v.z * g + bb); h[3] = (f16)(v.w * g + bb);
            *(f16x4*)&TT[c][n] = h;
        }
        __syncthreads();
        for (int i = 0; i < 4; i++) {
            int cid = threadIdx.x + i * 256;
            int cbl = cid >> 7, n = cid & 127;
            f16x8 v;
            for (int j = 0; j < 8; j++) v[j] = TT[cbl * 8 + j][n];
            *(f16x8*)(tb + (size_t)((cc >> 3) + cbl) * 1024 + n * 8) = v;
        }
    }
}

// ---------------- K2: QKV GEMM, BK=64, async staging, tiled outputs ----------------
__global__ __launch_bounds__(256, 2) void k_qkv(const f16* __restrict__ wT, const float* __restrict__ bias,
                                                const f16* __restrict__ xnT, f16* __restrict__ qF,
                                                f16* __restrict__ kTl, f16* __restrict__ vTl) {
    int nt = blockIdx.x, ot = blockIdx.y, b = blockIdx.z;
    int o0 = ot * 128;
    __shared__ union SM {
        struct { f16 As[8192]; f16 Bs[8192]; } s;
        f16 Cf[16384];
    } sm;
    __shared__ float biasS[128];
    if (threadIdx.x < 128) biasS[threadIdx.x] = bias[o0 + threadIdx.x];
    int tid = threadIdx.x, lane = tid & 63, wv = tid >> 6;
    int wr = wv >> 1, wc = wv & 1;
    int l15 = lane & 15, quad = lane >> 4;
    const f16* wA = wT + (size_t)ot * 65536;
    const f16* xB = xnT + ((size_t)(b * 8 + nt)) * 65536;
    f32x4 acc[4][4] = {};
    for (int kk = 0; kk < CH; kk += 64) {
        __syncthreads();
        const f16* sa = wA + (size_t)(kk >> 3) * 1024;
        const f16* sb = xB + (size_t)(kk >> 3) * 1024;
#pragma unroll
        for (int i = 0; i < 4; i++) {
            int s = wv * 4 + i;
            gld16(sa + (size_t)(s * 64 + lane) * 8, sm.s.As + s * 512);
            gld16(sb + (size_t)(s * 64 + lane) * 8, sm.s.Bs + s * 512);
        }
        __syncthreads();
#pragma unroll
        for (int dk = 0; dk < 2; dk++) {
            f16x8 af[4], bf[4];
#pragma unroll
            for (int t = 0; t < 4; t++) {
                af[t] = *(const f16x8*)(sm.s.As + (dk * 4 + quad) * 1024 + (wr * 64 + t * 16 + l15) * 8);
                bf[t] = *(const f16x8*)(sm.s.Bs + (dk * 4 + quad) * 1024 + (wc * 64 + t * 16 + l15) * 8);
            }
#pragma unroll
            for (int tm = 0; tm < 4; tm++)
#pragma unroll
                for (int tn = 0; tn < 4; tn++)
                    acc[tm][tn] = __builtin_amdgcn_mfma_f32_16x16x32_f16(af[tm], bf[tn], acc[tm][tn], 0, 0, 0);
        }
    }
    __syncthreads();
    int which = ot >> 2, h = ot & 3;
#pragma unroll
    for (int tm = 0; tm < 4; tm++)
#pragma unroll
        for (int tn = 0; tn < 4; tn++)
#pragma unroll
            for (int r = 0; r < 4; r++) {
                int o = wr * 64 + tm * 16 + quad * 4 + r;
                int n = wc * 64 + tn * 16 + l15;
                f16 v = (f16)(acc[tm][tn][r] + biasS[o]);
                int addr;
                if (which == 0)
                    addr = (((n >> 5) * 2 + ((n >> 4) & 1)) * 4 + (o >> 5)) * 512
                         + ((o >> 3) & 3) * 128 + (n & 15) * 8 + (o & 7);
                else if (which == 1)
                    addr = (o >> 3) * 1024 + n * 8 + (o & 7);
                else
                    addr = (n >> 3) * 1024 + o * 8 + (n & 7);
                sm.Cf[addr] = v;
            }
    __syncthreads();
    f16* tb = (which == 0) ? (qF + ((size_t)((b * 4 + h) * 8 + nt)) * 16384)
            : (which == 1) ? (kTl + ((size_t)((b * 4 + h) * 8 + nt)) * 16384)
                           : (vTl + ((size_t)((b * 4 + h) * 8 + nt)) * 16384);
#pragma unroll
    for (int i = 0; i < 8; i++) {
        int cid = tid + i * 256;
        *(f16x8*)(tb + (size_t)cid * 8) = *(const f16x8*)(sm.Cf + cid * 8);
    }
}

// ---------------- K3: flash attention v4 ----------------
// S^T = K Q^T (softmax reductions mostly in-lane), O^T = V^T P.
// Register ping-pong prefetch of next K/V tile; LDS 64 KB -> 2 blocks/CU.
__global__ __launch_bounds__(256, 2) void k_attn(const f16* __restrict__ qF, const f16* __restrict__ kTl,
                                                 const f16* __restrict__ vTl, f16* __restrict__ oT) {
    int bid = blockIdx.x;
    int nt = bid >> 6, group = bid & 63;      // all 8 nt of a group share bid%8 -> same XCD
    int b = group >> 2, h = group & 3;
    extern __shared__ f16 smem[];
    f16* KP = smem;              // K [dblk(16)][m(128)][8], later P [n][m swizzled]
    f16* Vl = smem + 16384;      // V [mblk(16)][c(128)][8]
    const f16* qb = qF + ((size_t)(group * 8 + nt)) * 16384;
    const f16* kb = kTl + (size_t)group * 8 * 16384;
    const f16* vb = vTl + (size_t)group * 8 * 16384;
    int tid = threadIdx.x, lane = tid & 63, wv = tid >> 6;
    int l15 = lane & 15, quad = lane >> 4;

    // Q fragments (also valid as B-operand), scale folded
    f16x8 aq[2][4];
#pragma unroll
    for (int t = 0; t < 2; t++)
#pragma unroll
        for (int dk = 0; dk < 4; dk++) {
            int seg = (wv * 2 + t) * 4 + dk;
            f16x8 v = *(const f16x8*)(qb + seg * 512 + lane * 8);
            aq[t][dk] = v * (f16)0.08838834764831845f;
        }

    float m_i[2] = {-1e30f, -1e30f}, l_i[2] = {0.f, 0.f};
    f32x4 oaccT[2][8] = {};   // [tr(n-tile)][tc(c-tile)], D[c-local][n-local]

    // prologue: prefetch tile 0 into registers
    f16x8 kbuf[8], vbuf[8];
#pragma unroll
    for (int i = 0; i < 8; i++) {
        int s = wv * 8 + i;
        kbuf[i] = *(const f16x8*)(kb + (size_t)(s * 64 + lane) * 8);
        vbuf[i] = *(const f16x8*)(vb + (size_t)(s * 64 + lane) * 8);
    }

    for (int mc = 0; mc < 8; mc++) {
        __syncthreads();  // (A) prev-iter LDS reads done
#pragma unroll
        for (int i = 0; i < 8; i++) {
            int s = wv * 8 + i;
            *(f16x8*)&KP[s * 512 + lane * 8] = kbuf[i];
            *(f16x8*)&Vl[s * 512 + lane * 8] = vbuf[i];
        }
        __syncthreads();  // (B) staged

        // S^T = K Q^T : D[m-local=quad*4+r][n-local=l15]
        f32x4 st[2][8] = {};
#pragma unroll
        for (int dk = 0; dk < 4; dk++) {
            f16x8 kf[8];
#pragma unroll
            for (int t = 0; t < 8; t++)
                kf[t] = *(const f16x8*)&KP[(dk * 4 + quad) * 1024 + (t * 16 + l15) * 8];
#pragma unroll
            for (int tr = 0; tr < 2; tr++)
#pragma unroll
                for (int tc = 0; tc < 8; tc++)
                    st[tr][tc] = __builtin_amdgcn_mfma_f32_16x16x32_f16(kf[tc], aq[tr][dk], st[tr][tc], 0, 0, 0);
        }

        // online softmax: in-lane over 32 m-values, 2 shuffles across quads
#pragma unroll
        for (int tr = 0; tr < 2; tr++) {
            float mx = -1e30f;
#pragma unroll
            for (int tc = 0; tc < 8; tc++)
#pragma unroll
                for (int r = 0; r < 4; r++) mx = fmaxf(mx, st[tr][tc][r]);
            mx = fmaxf(mx, __shfl_xor(mx, 16));
            mx = fmaxf(mx, __shfl_xor(mx, 32));
            float mnew = fmaxf(m_i[tr], mx);
            float alpha = __expf(m_i[tr] - mnew);
            m_i[tr] = mnew;
            float rs = 0.f;
#pragma unroll
            for (int tc = 0; tc < 8; tc++)
#pragma unroll
                for (int r = 0; r < 4; r++) {
                    float p = __expf(st[tr][tc][r] - mnew);
                    st[tr][tc][r] = p;
                    rs += p;
                }
            rs += __shfl_xor(rs, 16);
            rs += __shfl_xor(rs, 32);
            l_i[tr] = l_i[tr] * alpha + rs;
#pragma unroll
            for (int tc = 0; tc < 8; tc++) {
                oaccT[tr][tc].x *= alpha; oaccT[tr][tc].y *= alpha;
                oaccT[tr][tc].z *= alpha; oaccT[tr][tc].w *= alpha;
            }
        }

        __syncthreads();  // (C) all K reads done; KP becomes P

        // P[n][m] store, 8B-chunk XOR swizzle: elem (n,m) -> n*128 + ((m>>3)^(n&15))*8 + (m&7)
#pragma unroll
        for (int tr = 0; tr < 2; tr++) {
            int n = wv * 32 + tr * 16 + l15;
#pragma unroll
            for (int tc = 0; tc < 8; tc++) {
                int blk = tc * 2 + (quad >> 1);
                f16x4 pv;
#pragma unroll
                for (int r = 0; r < 4; r++) pv[r] = (f16)st[tr][tc][r];
                *(f16x4*)&KP[n * 128 + ((blk ^ (n & 15)) << 3) + ((quad & 1) << 2)] = pv;
            }
        }

        // prefetch next K/V tile into registers (overlaps PV + barrier + staging)
        if (mc < 7) {
            const f16* ks = kb + (size_t)(mc + 1) * 16384;
            const f16* vs = vb + (size_t)(mc + 1) * 16384;
#pragma unroll
            for (int i = 0; i < 8; i++) {
                int s = wv * 8 + i;
                kbuf[i] = *(const f16x8*)(ks + (size_t)(s * 64 + lane) * 8);
                vbuf[i] = *(const f16x8*)(vs + (size_t)(s * 64 + lane) * 8);
            }
        }

        // O^T += V^T P : A = V^T rows c, B = P cols n
#pragma unroll
        for (int mk = 0; mk < 4; mk++) {
            f16x8 vf[8], pf[2];
#pragma unroll
            for (int t = 0; t < 8; t++)
                vf[t] = *(const f16x8*)&Vl[(mk * 4 + quad) * 1024 + (t * 16 + l15) * 8];
#pragma unroll
            for (int tr = 0; tr < 2; tr++) {
                int n = wv * 32 + tr * 16 + l15;
                int blk = mk * 4 + quad;
                pf[tr] = *(const f16x8*)&KP[n * 128 + ((blk ^ (n & 15)) << 3)];
            }
#pragma unroll
            for (int tr = 0; tr < 2; tr++)
#pragma unroll
                for (int tc = 0; tc < 8; tc++)
                    oaccT[tr][tc] = __builtin_amdgcn_mfma_f32_16x16x32_f16(vf[tc], pf[tr], oaccT[tr][tc], 0, 0, 0);
        }
    }

    // epilogue: direct global store, f16x4 per (tr,tc)
    f16* ob = oT + ((size_t)(b * 8 + nt)) * 65536;
#pragma unroll
    for (int tr = 0; tr < 2; tr++) {
        float inv = 1.f / l_i[tr];
        int n = wv * 32 + tr * 16 + l15;
#pragma unroll
        for (int tc = 0; tc < 8; tc++) {
            f16x4 ov;
#pragma unroll
            for (int r = 0; r < 4; r++) ov[r] = (f16)(oaccT[tr][tc][r] * inv);
            *(f16x4*)(ob + (size_t)(h * 16 + tc * 2 + (quad >> 1)) * 1024 + n * 8 + ((quad & 1) << 2)) = ov;
        }
    }
}

// ---------------- K4: proj GEMM + bias + residual -> fp32 out ----------------
__global__ __launch_bounds__(256, 2) void k_proj(const f16* __restrict__ wT, const float* __restrict__ bias,
                                                 const f16* __restrict__ oT, const float* __restrict__ x,
                                                 float* __restrict__ out) {
    int nt = blockIdx.x, ot = blockIdx.y, b = blockIdx.z;
    int n0 = nt * 128, o0 = ot * 128;
    __shared__ union SM {
        struct { f16 As[8192]; f16 Bs[8192]; } s;
        f16 Cs[128][136];
    } sm;
    __shared__ float biasS[128];
    if (threadIdx.x < 128) biasS[threadIdx.x] = bias[o0 + threadIdx.x];
    int tid = threadIdx.x, lane = tid & 63, wv = tid >> 6;
    int wr = wv >> 1, wc = wv & 1;
    int l15 = lane & 15, quad = lane >> 4;
    const f16* wA = wT + (size_t)ot * 65536;
    const f16* xB = oT + ((size_t)(b * 8 + nt)) * 65536;
    f32x4 acc[4][4] = {};
    for (int kk = 0; kk < CH; kk += 64) {
        __syncthreads();
        const f16* sa = wA + (size_t)(kk >> 3) * 1024;
        const f16* sb = xB + (size_t)(kk >> 3) * 1024;
#pragma unroll
        for (int i = 0; i < 4; i++) {
            int s = wv * 4 + i;
            gld16(sa + (size_t)(s * 64 + lane) * 8, sm.s.As + s * 512);
            gld16(sb + (size_t)(s * 64 + lane) * 8, sm.s.Bs + s * 512);
        }
        __syncthreads();
#pragma unroll
        for (int dk = 0; dk < 2; dk++) {
            f16x8 af[4], bf[4];
#pragma unroll
            for (int t = 0; t < 4; t++) {
                af[t] = *(const f16x8*)(sm.s.As + (dk * 4 + quad) * 1024 + (wr * 64 + t * 16 + l15) * 8);
                bf[t] = *(const f16x8*)(sm.s.Bs + (dk * 4 + quad) * 1024 + (wc * 64 + t * 16 + l15) * 8);
            }
#pragma unroll
            for (int tm = 0; tm < 4; tm++)
#pragma unroll
                for (int tn = 0; tn < 4; tn++)
                    acc[tm][tn] = __builtin_amdgcn_mfma_f32_16x16x32_f16(af[tm], bf[tn], acc[tm][tn], 0, 0, 0);
        }
    }
    __syncthreads();
#pragma unroll
    for (int tm = 0; tm < 4; tm++)
#pragma unroll
        for (int tn = 0; tn < 4; tn++)
#pragma unroll
            for (int r = 0; r < 4; r++) {
                int o = wr * 64 + tm * 16 + quad * 4 + r;
                int n = wc * 64 + tn * 16 + l15;
                sm.Cs[o][n] = (f16)(acc[tm][tn][r] + biasS[o]);
            }
    __syncthreads();
#pragma unroll
    for (int i = 0; i < 8; i++) {
        int cid = tid + i * 256;
        int row = cid >> 4, off = (cid & 15) * 8;
        f16x8 v = *(const f16x8*)&sm.Cs[row][off];
        size_t gofs = ((size_t)(b * CH) + o0 + row) * NPIX + n0 + off;
        const float* xp = x + gofs;
        float* op = out + gofs;
        f32x4 o0v, o1v;
        o0v.x = xp[0] + (float)v[0]; o0v.y = xp[1] + (float)v[1];
        o0v.z = xp[2] + (float)v[2]; o0v.w = xp[3] + (float)v[3];
        o1v.x = xp[4] + (float)v[4]; o1v.y = xp[5] + (float)v[5];
        o1v.z = xp[6] + (float)v[6]; o1v.w = xp[7] + (float)v[7];
        *(f32x4*)op = o0v; *(f32x4*)(op + 4) = o1v;
    }
}

extern "C" void kernel_launch(void* const* d_in, const int* in_sizes, int n_in,
                              void* d_out, int out_size, void* d_ws, size_t ws_size,
                              hipStream_t stream) {
    const float* x     = (const float*)d_in[0];
    const float* gamma = (const float*)d_in[1];
    const float* beta  = (const float*)d_in[2];
    const float* wqkv  = (const float*)d_in[3];
    const float* bqkv  = (const float*)d_in[4];
    const float* wproj = (const float*)d_in[5];
    const float* bproj = (const float*)d_in[6];
    float* out = (float*)d_out;

    char* p = (char*)d_ws;
    float2* stats = (float2*)p;   p += 16 * 32 * sizeof(float2);
    f16* wqT = (f16*)p;           p += (size_t)3 * CH * CH * 2;
    f16* wpT = (f16*)p;           p += (size_t)CH * CH * 2;
    f16* xnT = (f16*)p;           p += (size_t)BATCH * NPIX * CH * 2;
    f16* qF  = (f16*)p;           p += (size_t)BATCH * HEADS * NPIX * HD * 2;
    f16* kTl = (f16*)p;           p += (size_t)BATCH * HEADS * NPIX * HD * 2;
    f16* vTl = (f16*)p;           p += (size_t)BATCH * HEADS * NPIX * HD * 2;
    f16* oT  = (f16*)p;           p += (size_t)BATCH * NPIX * CH * 2;

    k_convert<<<dim3(384), 256, 0, stream>>>(wqkv, wproj, wqT, wpT);
    k_stats<<<dim3(BATCH * GROUPS), 256, 0, stream>>>(x, stats);
    k_norm_t<<<dim3(8, BATCH), 256, 0, stream>>>(x, gamma, beta, stats, xnT);
    k_qkv<<<dim3(8, 12, BATCH), 256, 0, stream>>>(wqT, bqkv, xnT, qF, kTl, vTl);

    hipFuncSetAttribute((const void*)k_attn, hipFuncAttributeMaxDynamicSharedMemorySize, 65536);
    k_attn<<<dim3(512), 256, 65536, stream>>>(qF, kTl, vTl, oT);

    k_proj<<<dim3(8, 4, BATCH), 256, 0, stream>>>(wpT, bproj, oT, x, out);
}

// Round 5
// 256.087 us; speedup vs baseline: 1.6823x; 1.2039x over previous
//
#include <hip/hip_runtime.h>

#define CH 512
#define HEADS 4
#define HD 128
#define NPIX 1024
#define BATCH 16
#define GROUPS 32
#define GSZ 16
#define EPS 1e-5f

typedef _Float16 f16;
typedef _Float16 f16x8 __attribute__((ext_vector_type(8)));
typedef _Float16 f16x4 __attribute__((ext_vector_type(4)));
typedef float f32x4 __attribute__((ext_vector_type(4)));

__device__ __forceinline__ void gld16(const f16* g, f16* l) {
    __builtin_amdgcn_global_load_lds((__attribute__((address_space(1))) const void*)g,
                                     (__attribute__((address_space(3))) void*)l, 16, 0, 0);
}

// ---------------- K0: convert + pre-transpose weights ----------------
__global__ void k_convert(const float* __restrict__ wq, const float* __restrict__ wp,
                          f16* __restrict__ wqT, f16* __restrict__ wpT) {
    int c = blockIdx.x * 256 + threadIdx.x;
    {
        int ot = c >> 13, kbl = (c >> 7) & 63, ol = c & 127;
        const float* s = wq + ((size_t)(ot * 128 + ol)) * CH + kbl * 8;
        f32x4 a = *(const f32x4*)s, b = *(const f32x4*)(s + 4);
        f16x8 v;
        v[0] = (f16)a.x; v[1] = (f16)a.y; v[2] = (f16)a.z; v[3] = (f16)a.w;
        v[4] = (f16)b.x; v[5] = (f16)b.y; v[6] = (f16)b.z; v[7] = (f16)b.w;
        *(f16x8*)(wqT + (size_t)c * 8) = v;
    }
    if (c < 32768) {
        int ot = c >> 13, kbl = (c >> 7) & 63, ol = c & 127;
        const float* s = wp + ((size_t)(ot * 128 + ol)) * CH + kbl * 8;
        f32x4 a = *(const f32x4*)s, b = *(const f32x4*)(s + 4);
        f16x8 v;
        v[0] = (f16)a.x; v[1] = (f16)a.y; v[2] = (f16)a.z; v[3] = (f16)a.w;
        v[4] = (f16)b.x; v[5] = (f16)b.y; v[6] = (f16)b.z; v[7] = (f16)b.w;
        *(f16x8*)(wpT + (size_t)c * 8) = v;
    }
}

// ---------------- K1a: groupnorm stats ----------------
__global__ void k_stats(const float* __restrict__ x, float2* __restrict__ stats) {
    int bg = blockIdx.x;
    const f32x4* b4 = (const f32x4*)(x + (size_t)bg * (GSZ * NPIX));
    float s = 0.f, ss = 0.f;
    for (int i = threadIdx.x; i < GSZ * NPIX / 4; i += 256) {
        f32x4 v = b4[i];
        s  += v.x + v.y + v.z + v.w;
        ss += v.x * v.x + v.y * v.y + v.z * v.z + v.w * v.w;
    }
    for (int off = 32; off; off >>= 1) { s += __shfl_down(s, off); ss += __shfl_down(ss, off); }
    __shared__ float as_[4], ass[4];
    int wv = threadIdx.x >> 6, ln = threadIdx.x & 63;
    if (ln == 0) { as_[wv] = s; ass[wv] = ss; }
    __syncthreads();
    if (threadIdx.x == 0) {
        float S = as_[0] + as_[1] + as_[2] + as_[3];
        float SS = ass[0] + ass[1] + ass[2] + ass[3];
        float mu = S / (GSZ * NPIX);
        float var = SS / (GSZ * NPIX) - mu * mu;
        stats[bg] = make_float2(mu, rsqrtf(var + EPS));
    }
}

// ---------------- K1b: normalize + transpose -> xnT tiled ----------------
__global__ void k_norm_t(const float* __restrict__ x, const float* __restrict__ gamma,
                         const float* __restrict__ beta, const float2* __restrict__ stats,
                         f16* __restrict__ xnT) {
    int nt = blockIdx.x, b = blockIdx.y;
    int n0 = nt * 128;
    __shared__ float gS[CH], bS[CH];
    __shared__ float2 stS[GROUPS];
    __shared__ f16 TT[64][136];
    for (int i = threadIdx.x; i < CH; i += 256) { gS[i] = gamma[i]; bS[i] = beta[i]; }
    if (threadIdx.x < GROUPS) stS[threadIdx.x] = stats[b * GROUPS + threadIdx.x];
    __syncthreads();
    f16* tb = xnT + ((size_t)(b * 8 + nt)) * 65536;
    for (int cc = 0; cc < CH; cc += 64) {
        __syncthreads();
        for (int i = 0; i < 8; i++) {
            int cid = threadIdx.x + i * 256;
            int c = cid >> 5;
            int n = (cid & 31) * 4;
            int cg = cc + c;
            f32x4 v = *(const f32x4*)(x + ((size_t)(b * CH + cg)) * NPIX + n0 + n);
            float2 st = stS[cg >> 4];
            float g = gS[cg] * st.y;
            float bb = bS[cg] - st.x * g;
            f16x4 h;
            h[0] = (f16)(v.x * g + bb); h[1] = (f16)(v.y * g + bb);
            h[2] = (f16)(v.z * g + bb); h[3] = (f16)(v.w * g + bb);
            *(f16x4*)&TT[c][n] = h;
        }
        __syncthreads();
        for (int i = 0; i < 4; i++) {
            int cid = threadIdx.x + i * 256;
            int cbl = cid >> 7, n = cid & 127;
            f16x8 v;
            for (int j = 0; j < 8; j++) v[j] = TT[cbl * 8 + j][n];
            *(f16x8*)(tb + (size_t)((cc >> 3) + cbl) * 1024 + n * 8) = v;
        }
    }
}

// ---------------- K2: QKV GEMM, BK=64, async staging, tiled outputs ----------------
__global__ __launch_bounds__(256, 2) void k_qkv(const f16* __restrict__ wT, const float* __restrict__ bias,
                                                const f16* __restrict__ xnT, f16* __restrict__ qF,
                                                f16* __restrict__ kTl, f16* __restrict__ vTl) {
    int nt = blockIdx.x, ot = blockIdx.y, b = blockIdx.z;
    int o0 = ot * 128;
    __shared__ union SM {
        struct { f16 As[8192]; f16 Bs[8192]; } s;
        f16 Cf[16384];
    } sm;
    __shared__ float biasS[128];
    if (threadIdx.x < 128) biasS[threadIdx.x] = bias[o0 + threadIdx.x];
    int tid = threadIdx.x, lane = tid & 63, wv = tid >> 6;
    int wr = wv >> 1, wc = wv & 1;
    int l15 = lane & 15, quad = lane >> 4;
    const f16* wA = wT + (size_t)ot * 65536;
    const f16* xB = xnT + ((size_t)(b * 8 + nt)) * 65536;
    f32x4 acc[4][4] = {};
    for (int kk = 0; kk < CH; kk += 64) {
        __syncthreads();
        const f16* sa = wA + (size_t)(kk >> 3) * 1024;
        const f16* sb = xB + (size_t)(kk >> 3) * 1024;
#pragma unroll
        for (int i = 0; i < 4; i++) {
            int s = wv * 4 + i;
            gld16(sa + (size_t)(s * 64 + lane) * 8, sm.s.As + s * 512);
            gld16(sb + (size_t)(s * 64 + lane) * 8, sm.s.Bs + s * 512);
        }
        __syncthreads();
#pragma unroll
        for (int dk = 0; dk < 2; dk++) {
            f16x8 af[4], bf[4];
#pragma unroll
            for (int t = 0; t < 4; t++) {
                af[t] = *(const f16x8*)(sm.s.As + (dk * 4 + quad) * 1024 + (wr * 64 + t * 16 + l15) * 8);
                bf[t] = *(const f16x8*)(sm.s.Bs + (dk * 4 + quad) * 1024 + (wc * 64 + t * 16 + l15) * 8);
            }
#pragma unroll
            for (int tm = 0; tm < 4; tm++)
#pragma unroll
                for (int tn = 0; tn < 4; tn++)
                    acc[tm][tn] = __builtin_amdgcn_mfma_f32_16x16x32_f16(af[tm], bf[tn], acc[tm][tn], 0, 0, 0);
        }
    }
    __syncthreads();
    int which = ot >> 2, h = ot & 3;
#pragma unroll
    for (int tm = 0; tm < 4; tm++)
#pragma unroll
        for (int tn = 0; tn < 4; tn++)
#pragma unroll
            for (int r = 0; r < 4; r++) {
                int o = wr * 64 + tm * 16 + quad * 4 + r;
                int n = wc * 64 + tn * 16 + l15;
                f16 v = (f16)(acc[tm][tn][r] + biasS[o]);
                int addr;
                if (which == 0)
                    addr = (((n >> 5) * 2 + ((n >> 4) & 1)) * 4 + (o >> 5)) * 512
                         + ((o >> 3) & 3) * 128 + (n & 15) * 8 + (o & 7);
                else if (which == 1)
                    addr = (o >> 3) * 1024 + n * 8 + (o & 7);
                else
                    addr = (n >> 3) * 1024 + o * 8 + (n & 7);
                sm.Cf[addr] = v;
            }
    __syncthreads();
    f16* tb = (which == 0) ? (qF + ((size_t)((b * 4 + h) * 8 + nt)) * 16384)
            : (which == 1) ? (kTl + ((size_t)((b * 4 + h) * 8 + nt)) * 16384)
                           : (vTl + ((size_t)((b * 4 + h) * 8 + nt)) * 16384);
#pragma unroll
    for (int i = 0; i < 8; i++) {
        int cid = tid + i * 256;
        *(f16x8*)(tb + (size_t)cid * 8) = *(const f16x8*)(sm.Cf + cid * 8);
    }
}

// ---------------- K3: flash attention v5 ----------------
// 512-thread blocks; one K/V stage serves TWO 128-row Q-tiles (waves 0-3: tile A,
// waves 4-7: tile B). Halves per-CU staged bytes per unit of MFMA work.
// LDS: KP (K tile, then P of tile A) 32 KB + Vl 32 KB + PB (P of tile B) 32 KB = 96 KB.
__global__ __launch_bounds__(512, 1) void k_attn(const f16* __restrict__ qF, const f16* __restrict__ kTl,
                                                 const f16* __restrict__ vTl, f16* __restrict__ oT) {
    int bid = blockIdx.x;                 // 256 blocks
    int ntp = bid >> 6, group = bid & 63; // all 4 ntp of a group share bid%8 -> same XCD
    int b = group >> 2, h = group & 3;
    extern __shared__ f16 smem[];
    f16* KP = smem;              // K [dblk(16)][m(128)][8]; later P of tile A
    f16* Vl = smem + 16384;      // V [mblk(16)][c(128)][8]
    f16* PB = smem + 32768;      // P of tile B
    int tid = threadIdx.x, lane = tid & 63, wv = tid >> 6;  // wv 0..7
    int wq = wv & 3;             // wave index within its Q-tile
    int tile = wv >> 2;          // 0 = tile A, 1 = tile B
    int nt = ntp * 2 + tile;
    int l15 = lane & 15, quad = lane >> 4;
    const f16* qb = qF + ((size_t)(group * 8 + nt)) * 16384;
    const f16* kb = kTl + (size_t)group * 8 * 16384;
    const f16* vb = vTl + (size_t)group * 8 * 16384;
    f16* Preg = tile ? PB : KP;

    // Q fragments, scale folded
    f16x8 aq[2][4];
#pragma unroll
    for (int t = 0; t < 2; t++)
#pragma unroll
        for (int dk = 0; dk < 4; dk++) {
            int seg = (wq * 2 + t) * 4 + dk;
            f16x8 v = *(const f16x8*)(qb + seg * 512 + lane * 8);
            aq[t][dk] = v * (f16)0.08838834764831845f;
        }

    float m_i[2] = {-1e30f, -1e30f}, l_i[2] = {0.f, 0.f};
    f32x4 oaccT[2][8] = {};

    // staging role: waves 0-3 stage K, waves 4-7 stage V; 8 chunks/lane each
    const f16* sbase = tile ? vb : kb;
    f16* dstL = tile ? Vl : KP;
    f16x8 buf[8];
#pragma unroll
    for (int i = 0; i < 8; i++)
        buf[i] = *(const f16x8*)(sbase + (size_t)((wq * 8 + i) * 64 + lane) * 8);

    for (int mc = 0; mc < 8; mc++) {
        __syncthreads();  // (A) prev-iter V/P reads done
#pragma unroll
        for (int i = 0; i < 8; i++)
            *(f16x8*)&dstL[(wq * 8 + i) * 512 + lane * 8] = buf[i];
        __syncthreads();  // (B) staged

        // S^T = K Q^T : D[m-local=quad*4+r][n-local=l15]
        f32x4 st[2][8] = {};
#pragma unroll
        for (int dk = 0; dk < 4; dk++) {
            f16x8 kf[8];
#pragma unroll
            for (int t = 0; t < 8; t++)
                kf[t] = *(const f16x8*)&KP[(dk * 4 + quad) * 1024 + (t * 16 + l15) * 8];
#pragma unroll
            for (int tr = 0; tr < 2; tr++)
#pragma unroll
                for (int tc = 0; tc < 8; tc++)
                    st[tr][tc] = __builtin_amdgcn_mfma_f32_16x16x32_f16(kf[tc], aq[tr][dk], st[tr][tc], 0, 0, 0);
        }

        // online softmax: in-lane over 32 m-values + 2 shuffles
#pragma unroll
        for (int tr = 0; tr < 2; tr++) {
            float mx = -1e30f;
#pragma unroll
            for (int tc = 0; tc < 8; tc++)
#pragma unroll
                for (int r = 0; r < 4; r++) mx = fmaxf(mx, st[tr][tc][r]);
            mx = fmaxf(mx, __shfl_xor(mx, 16));
            mx = fmaxf(mx, __shfl_xor(mx, 32));
            float mnew = fmaxf(m_i[tr], mx);
            float alpha = __expf(m_i[tr] - mnew);
            m_i[tr] = mnew;
            float rs = 0.f;
#pragma unroll
            for (int tc = 0; tc < 8; tc++)
#pragma unroll
                for (int r = 0; r < 4; r++) {
                    float p = __expf(st[tr][tc][r] - mnew);
                    st[tr][tc][r] = p;
                    rs += p;
                }
            rs += __shfl_xor(rs, 16);
            rs += __shfl_xor(rs, 32);
            l_i[tr] = l_i[tr] * alpha + rs;
#pragma unroll
            for (int tc = 0; tc < 8; tc++) {
                oaccT[tr][tc].x *= alpha; oaccT[tr][tc].y *= alpha;
                oaccT[tr][tc].z *= alpha; oaccT[tr][tc].w *= alpha;
            }
        }

        __syncthreads();  // (C) all K reads done; KP becomes P(tile A)

        // P[n][m] store into own region, 8B-chunk XOR swizzle
#pragma unroll
        for (int tr = 0; tr < 2; tr++) {
            int n = wq * 32 + tr * 16 + l15;
#pragma unroll
            for (int tc = 0; tc < 8; tc++) {
                int blk = tc * 2 + (quad >> 1);
                f16x4 pv;
#pragma unroll
                for (int r = 0; r < 4; r++) pv[r] = (f16)st[tr][tc][r];
                *(f16x4*)&Preg[n * 128 + ((blk ^ (n & 15)) << 3) + ((quad & 1) << 2)] = pv;
            }
        }

        // prefetch next K or V tile into registers
        if (mc < 7) {
            const f16* s = sbase + (size_t)(mc + 1) * 16384;
#pragma unroll
            for (int i = 0; i < 8; i++)
                buf[i] = *(const f16x8*)(s + (size_t)((wq * 8 + i) * 64 + lane) * 8);
        }

        // O^T += V^T P
#pragma unroll
        for (int mk = 0; mk < 4; mk++) {
            f16x8 vf[8], pf[2];
#pragma unroll
            for (int t = 0; t < 8; t++)
                vf[t] = *(const f16x8*)&Vl[(mk * 4 + quad) * 1024 + (t * 16 + l15) * 8];
#pragma unroll
            for (int tr = 0; tr < 2; tr++) {
                int n = wq * 32 + tr * 16 + l15;
                int blk = mk * 4 + quad;
                pf[tr] = *(const f16x8*)&Preg[n * 128 + ((blk ^ (n & 15)) << 3)];
            }
#pragma unroll
            for (int tr = 0; tr < 2; tr++)
#pragma unroll
                for (int tc = 0; tc < 8; tc++)
                    oaccT[tr][tc] = __builtin_amdgcn_mfma_f32_16x16x32_f16(vf[tc], pf[tr], oaccT[tr][tc], 0, 0, 0);
        }
    }

    // epilogue: direct global store
    f16* ob = oT + ((size_t)(b * 8 + nt)) * 65536;
#pragma unroll
    for (int tr = 0; tr < 2; tr++) {
        float inv = 1.f / l_i[tr];
        int n = wq * 32 + tr * 16 + l15;
#pragma unroll
        for (int tc = 0; tc < 8; tc++) {
            f16x4 ov;
#pragma unroll
            for (int r = 0; r < 4; r++) ov[r] = (f16)(oaccT[tr][tc][r] * inv);
            *(f16x4*)(ob + (size_t)(h * 16 + tc * 2 + (quad >> 1)) * 1024 + n * 8 + ((quad & 1) << 2)) = ov;
        }
    }
}

// ---------------- K4: proj GEMM + bias + residual -> fp32 out ----------------
__global__ __launch_bounds__(256, 2) void k_proj(const f16* __restrict__ wT, const float* __restrict__ bias,
                                                 const f16* __restrict__ oT, const float* __restrict__ x,
                                                 float* __restrict__ out) {
    int nt = blockIdx.x, ot = blockIdx.y, b = blockIdx.z;
    int n0 = nt * 128, o0 = ot * 128;
    __shared__ union SM {
        struct { f16 As[8192]; f16 Bs[8192]; } s;
        f16 Cs[128][136];
    } sm;
    __shared__ float biasS[128];
    if (threadIdx.x < 128) biasS[threadIdx.x] = bias[o0 + threadIdx.x];
    int tid = threadIdx.x, lane = tid & 63, wv = tid >> 6;
    int wr = wv >> 1, wc = wv & 1;
    int l15 = lane & 15, quad = lane >> 4;
    const f16* wA = wT + (size_t)ot * 65536;
    const f16* xB = oT + ((size_t)(b * 8 + nt)) * 65536;
    f32x4 acc[4][4] = {};
    for (int kk = 0; kk < CH; kk += 64) {
        __syncthreads();
        const f16* sa = wA + (size_t)(kk >> 3) * 1024;
        const f16* sb = xB + (size_t)(kk >> 3) * 1024;
#pragma unroll
        for (int i = 0; i < 4; i++) {
            int s = wv * 4 + i;
            gld16(sa + (size_t)(s * 64 + lane) * 8, sm.s.As + s * 512);
            gld16(sb + (size_t)(s * 64 + lane) * 8, sm.s.Bs + s * 512);
        }
        __syncthreads();
#pragma unroll
        for (int dk = 0; dk < 2; dk++) {
            f16x8 af[4], bf[4];
#pragma unroll
            for (int t = 0; t < 4; t++) {
                af[t] = *(const f16x8*)(sm.s.As + (dk * 4 + quad) * 1024 + (wr * 64 + t * 16 + l15) * 8);
                bf[t] = *(const f16x8*)(sm.s.Bs + (dk * 4 + quad) * 1024 + (wc * 64 + t * 16 + l15) * 8);
            }
#pragma unroll
            for (int tm = 0; tm < 4; tm++)
#pragma unroll
                for (int tn = 0; tn < 4; tn++)
                    acc[tm][tn] = __builtin_amdgcn_mfma_f32_16x16x32_f16(af[tm], bf[tn], acc[tm][tn], 0, 0, 0);
        }
    }
    __syncthreads();
#pragma unroll
    for (int tm = 0; tm < 4; tm++)
#pragma unroll
        for (int tn = 0; tn < 4; tn++)
#pragma unroll
            for (int r = 0; r < 4; r++) {
                int o = wr * 64 + tm * 16 + quad * 4 + r;
                int n = wc * 64 + tn * 16 + l15;
                sm.Cs[o][n] = (f16)(acc[tm][tn][r] + biasS[o]);
            }
    __syncthreads();
#pragma unroll
    for (int i = 0; i < 8; i++) {
        int cid = tid + i * 256;
        int row = cid >> 4, off = (cid & 15) * 8;
        f16x8 v = *(const f16x8*)&sm.Cs[row][off];
        size_t gofs = ((size_t)(b * CH) + o0 + row) * NPIX + n0 + off;
        const float* xp = x + gofs;
        float* op = out + gofs;
        f32x4 o0v, o1v;
        o0v.x = xp[0] + (float)v[0]; o0v.y = xp[1] + (float)v[1];
        o0v.z = xp[2] + (float)v[2]; o0v.w = xp[3] + (float)v[3];
        o1v.x = xp[4] + (float)v[4]; o1v.y = xp[5] + (float)v[5];
        o1v.z = xp[6] + (float)v[6]; o1v.w = xp[7] + (float)v[7];
        *(f32x4*)op = o0v; *(f32x4*)(op + 4) = o1v;
    }
}

extern "C" void kernel_launch(void* const* d_in, const int* in_sizes, int n_in,
                              void* d_out, int out_size, void* d_ws, size_t ws_size,
                              hipStream_t stream) {
    const float* x     = (const float*)d_in[0];
    const float* gamma = (const float*)d_in[1];
    const float* beta  = (const float*)d_in[2];
    const float* wqkv  = (const float*)d_in[3];
    const float* bqkv  = (const float*)d_in[4];
    const float* wproj = (const float*)d_in[5];
    const float* bproj = (const float*)d_in[6];
    float* out = (float*)d_out;

    char* p = (char*)d_ws;
    float2* stats = (float2*)p;   p += 16 * 32 * sizeof(float2);
    f16* wqT = (f16*)p;           p += (size_t)3 * CH * CH * 2;
    f16* wpT = (f16*)p;           p += (size_t)CH * CH * 2;
    f16* xnT = (f16*)p;           p += (size_t)BATCH * NPIX * CH * 2;
    f16* qF  = (f16*)p;           p += (size_t)BATCH * HEADS * NPIX * HD * 2;
    f16* kTl = (f16*)p;           p += (size_t)BATCH * HEADS * NPIX * HD * 2;
    f16* vTl = (f16*)p;           p += (size_t)BATCH * HEADS * NPIX * HD * 2;
    f16* oT  = (f16*)p;           p += (size_t)BATCH * NPIX * CH * 2;

    k_convert<<<dim3(384), 256, 0, stream>>>(wqkv, wproj, wqT, wpT);
    k_stats<<<dim3(BATCH * GROUPS), 256, 0, stream>>>(x, stats);
    k_norm_t<<<dim3(8, BATCH), 256, 0, stream>>>(x, gamma, beta, stats, xnT);
    k_qkv<<<dim3(8, 12, BATCH), 256, 0, stream>>>(wqT, bqkv, xnT, qF, kTl, vTl);

    hipFuncSetAttribute((const void*)k_attn, hipFuncAttributeMaxDynamicSharedMemorySize, 98304);
    k_attn<<<dim3(256), 512, 98304, stream>>>(qF, kTl, vTl, oT);

    k_proj<<<dim3(8, 4, BATCH), 256, 0, stream>>>(wpT, bproj, oT, x, out);
}

// Round 6
// 249.887 us; speedup vs baseline: 1.7240x; 1.0248x over previous
//
#include <hip/hip_runtime.h>

#define CH 512
#define HEADS 4
#define HD 128
#define NPIX 1024
#define BATCH 16
#define GROUPS 32
#define GSZ 16
#define EPS 1e-5f

typedef _Float16 f16;
typedef _Float16 f16x8 __attribute__((ext_vector_type(8)));
typedef _Float16 f16x4 __attribute__((ext_vector_type(4)));
typedef float f32x4 __attribute__((ext_vector_type(4)));

// ---------------- K0: convert + pre-transpose weights ----------------
__global__ void k_convert(const float* __restrict__ wq, const float* __restrict__ wp,
                          f16* __restrict__ wqT, f16* __restrict__ wpT) {
    int c = blockIdx.x * 256 + threadIdx.x;
    {
        int ot = c >> 13, kbl = (c >> 7) & 63, ol = c & 127;
        const float* s = wq + ((size_t)(ot * 128 + ol)) * CH + kbl * 8;
        f32x4 a = *(const f32x4*)s, b = *(const f32x4*)(s + 4);
        f16x8 v;
        v[0] = (f16)a.x; v[1] = (f16)a.y; v[2] = (f16)a.z; v[3] = (f16)a.w;
        v[4] = (f16)b.x; v[5] = (f16)b.y; v[6] = (f16)b.z; v[7] = (f16)b.w;
        *(f16x8*)(wqT + (size_t)c * 8) = v;
    }
    if (c < 32768) {
        int ot = c >> 13, kbl = (c >> 7) & 63, ol = c & 127;
        const float* s = wp + ((size_t)(ot * 128 + ol)) * CH + kbl * 8;
        f32x4 a = *(const f32x4*)s, b = *(const f32x4*)(s + 4);
        f16x8 v;
        v[0] = (f16)a.x; v[1] = (f16)a.y; v[2] = (f16)a.z; v[3] = (f16)a.w;
        v[4] = (f16)b.x; v[5] = (f16)b.y; v[6] = (f16)b.z; v[7] = (f16)b.w;
        *(f16x8*)(wpT + (size_t)c * 8) = v;
    }
}

// ---------------- K1a: groupnorm stats ----------------
__global__ void k_stats(const float* __restrict__ x, float2* __restrict__ stats) {
    int bg = blockIdx.x;
    const f32x4* b4 = (const f32x4*)(x + (size_t)bg * (GSZ * NPIX));
    float s = 0.f, ss = 0.f;
    for (int i = threadIdx.x; i < GSZ * NPIX / 4; i += 256) {
        f32x4 v = b4[i];
        s  += v.x + v.y + v.z + v.w;
        ss += v.x * v.x + v.y * v.y + v.z * v.z + v.w * v.w;
    }
    for (int off = 32; off; off >>= 1) { s += __shfl_down(s, off); ss += __shfl_down(ss, off); }
    __shared__ float as_[4], ass[4];
    int wv = threadIdx.x >> 6, ln = threadIdx.x & 63;
    if (ln == 0) { as_[wv] = s; ass[wv] = ss; }
    __syncthreads();
    if (threadIdx.x == 0) {
        float S = as_[0] + as_[1] + as_[2] + as_[3];
        float SS = ass[0] + ass[1] + ass[2] + ass[3];
        float mu = S / (GSZ * NPIX);
        float var = SS / (GSZ * NPIX) - mu * mu;
        stats[bg] = make_float2(mu, rsqrtf(var + EPS));
    }
}

// ---------------- K1b: normalize + transpose -> xnT tiled ----------------
__global__ void k_norm_t(const float* __restrict__ x, const float* __restrict__ gamma,
                         const float* __restrict__ beta, const float2* __restrict__ stats,
                         f16* __restrict__ xnT) {
    int nt = blockIdx.x, b = blockIdx.y;
    int n0 = nt * 128;
    __shared__ float gS[CH], bS[CH];
    __shared__ float2 stS[GROUPS];
    __shared__ f16 TT[64][136];
    for (int i = threadIdx.x; i < CH; i += 256) { gS[i] = gamma[i]; bS[i] = beta[i]; }
    if (threadIdx.x < GROUPS) stS[threadIdx.x] = stats[b * GROUPS + threadIdx.x];
    __syncthreads();
    f16* tb = xnT + ((size_t)(b * 8 + nt)) * 65536;
    for (int cc = 0; cc < CH; cc += 64) {
        __syncthreads();
        for (int i = 0; i < 8; i++) {
            int cid = threadIdx.x + i * 256;
            int c = cid >> 5;
            int n = (cid & 31) * 4;
            int cg = cc + c;
            f32x4 v = *(const f32x4*)(x + ((size_t)(b * CH + cg)) * NPIX + n0 + n);
            float2 st = stS[cg >> 4];
            float g = gS[cg] * st.y;
            float bb = bS[cg] - st.x * g;
            f16x4 h;
            h[0] = (f16)(v.x * g + bb); h[1] = (f16)(v.y * g + bb);
            h[2] = (f16)(v.z * g + bb); h[3] = (f16)(v.w * g + bb);
            *(f16x4*)&TT[c][n] = h;
        }
        __syncthreads();
        for (int i = 0; i < 4; i++) {
            int cid = threadIdx.x + i * 256;
            int cbl = cid >> 7, n = cid & 127;
            f16x8 v;
            for (int j = 0; j < 8; j++) v[j] = TT[cbl * 8 + j][n];
            *(f16x8*)(tb + (size_t)((cc >> 3) + cbl) * 1024 + n * 8) = v;
        }
    }
}

// ---------------- K2: QKV GEMM, BK=64, register ping-pong prefetch ----------------
__global__ __launch_bounds__(256, 2) void k_qkv(const f16* __restrict__ wT, const float* __restrict__ bias,
                                                const f16* __restrict__ xnT, f16* __restrict__ qF,
                                                f16* __restrict__ kTl, f16* __restrict__ vTl) {
    int nt = blockIdx.x, ot = blockIdx.y, b = blockIdx.z;
    int o0 = ot * 128;
    __shared__ union SM {
        struct { f16 As[8192]; f16 Bs[8192]; } s;
        f16 Cf[16384];
    } sm;
    __shared__ float biasS[128];
    if (threadIdx.x < 128) biasS[threadIdx.x] = bias[o0 + threadIdx.x];
    int tid = threadIdx.x, lane = tid & 63, wv = tid >> 6;
    int wr = wv >> 1, wc = wv & 1;
    int l15 = lane & 15, quad = lane >> 4;
    const f16* wA = wT + (size_t)ot * 65536;
    const f16* xB = xnT + ((size_t)(b * 8 + nt)) * 65536;
    f32x4 acc[4][4] = {};
    // prologue: prefetch kk=0 tiles into registers
    f16x8 abuf[4], bbuf[4];
#pragma unroll
    for (int i = 0; i < 4; i++) {
        int s = wv * 4 + i;
        abuf[i] = *(const f16x8*)(wA + (size_t)(s * 64 + lane) * 8);
        bbuf[i] = *(const f16x8*)(xB + (size_t)(s * 64 + lane) * 8);
    }
    for (int kk = 0; kk < CH; kk += 64) {
        __syncthreads();
#pragma unroll
        for (int i = 0; i < 4; i++) {
            int s = wv * 4 + i;
            *(f16x8*)&sm.s.As[(s * 64 + lane) * 8] = abuf[i];
            *(f16x8*)&sm.s.Bs[(s * 64 + lane) * 8] = bbuf[i];
        }
        __syncthreads();
        if (kk < CH - 64) {
            const f16* sa = wA + (size_t)((kk + 64) >> 3) * 1024;
            const f16* sb = xB + (size_t)((kk + 64) >> 3) * 1024;
#pragma unroll
            for (int i = 0; i < 4; i++) {
                int s = wv * 4 + i;
                abuf[i] = *(const f16x8*)(sa + (size_t)(s * 64 + lane) * 8);
                bbuf[i] = *(const f16x8*)(sb + (size_t)(s * 64 + lane) * 8);
            }
        }
#pragma unroll
        for (int dk = 0; dk < 2; dk++) {
            f16x8 af[4], bf[4];
#pragma unroll
            for (int t = 0; t < 4; t++) {
                af[t] = *(const f16x8*)(sm.s.As + (dk * 4 + quad) * 1024 + (wr * 64 + t * 16 + l15) * 8);
                bf[t] = *(const f16x8*)(sm.s.Bs + (dk * 4 + quad) * 1024 + (wc * 64 + t * 16 + l15) * 8);
            }
#pragma unroll
            for (int tm = 0; tm < 4; tm++)
#pragma unroll
                for (int tn = 0; tn < 4; tn++)
                    acc[tm][tn] = __builtin_amdgcn_mfma_f32_16x16x32_f16(af[tm], bf[tn], acc[tm][tn], 0, 0, 0);
        }
    }
    __syncthreads();
    int which = ot >> 2, h = ot & 3;
#pragma unroll
    for (int tm = 0; tm < 4; tm++)
#pragma unroll
        for (int tn = 0; tn < 4; tn++)
#pragma unroll
            for (int r = 0; r < 4; r++) {
                int o = wr * 64 + tm * 16 + quad * 4 + r;
                int n = wc * 64 + tn * 16 + l15;
                f16 v = (f16)(acc[tm][tn][r] + biasS[o]);
                int addr;
                if (which == 0)
                    addr = (((n >> 5) * 2 + ((n >> 4) & 1)) * 4 + (o >> 5)) * 512
                         + ((o >> 3) & 3) * 128 + (n & 15) * 8 + (o & 7);
                else if (which == 1)
                    addr = (o >> 3) * 1024 + n * 8 + (o & 7);
                else
                    addr = (n >> 3) * 1024 + o * 8 + (n & 7);
                sm.Cf[addr] = v;
            }
    __syncthreads();
    f16* tb = (which == 0) ? (qF + ((size_t)((b * 4 + h) * 8 + nt)) * 16384)
            : (which == 1) ? (kTl + ((size_t)((b * 4 + h) * 8 + nt)) * 16384)
                           : (vTl + ((size_t)((b * 4 + h) * 8 + nt)) * 16384);
#pragma unroll
    for (int i = 0; i < 8; i++) {
        int cid = tid + i * 256;
        *(f16x8*)(tb + (size_t)cid * 8) = *(const f16x8*)(sm.Cf + cid * 8);
    }
}

// ---------------- K3: flash attention v6 ----------------
// 512 threads; one K/V stage serves two Q-tiles. P per-tile regions (wave-private
// rows) -> no K->P alias barrier. Epilogue via LDS + f16x8 coalesced stores
// (fixes 7x HBM write amplification of f16x4 partial-line stores).
// LDS: Kl 32K + Vl 32K + PA 32K + PB 32K = 128 KB -> 1 block/CU.
__global__ __launch_bounds__(512, 1) void k_attn(const f16* __restrict__ qF, const f16* __restrict__ kTl,
                                                 const f16* __restrict__ vTl, f16* __restrict__ oT) {
    int bid = blockIdx.x;                 // 256 blocks
    int ntp = bid >> 6, group = bid & 63; // group=(b,h); bid%8 stable -> XCD locality
    int b = group >> 2, h = group & 3;
    extern __shared__ f16 smem[];
    f16* Kl = smem;              // K [dblk(16)][m(128)][8]
    f16* Vl = smem + 16384;      // V [mblk(16)][c(128)][8]
    f16* PA = smem + 32768;      // P of tile A (swizzled [n][m])
    f16* PB = smem + 49152;      // P of tile B
    int tid = threadIdx.x, lane = tid & 63, wv = tid >> 6;  // wv 0..7
    int wq = wv & 3;
    int tile = wv >> 2;          // 0 = tile A, 1 = tile B
    int nt = ntp * 2 + tile;
    int l15 = lane & 15, quad = lane >> 4;
    const f16* qb = qF + ((size_t)(group * 8 + nt)) * 16384;
    const f16* kb = kTl + (size_t)group * 8 * 16384;
    const f16* vb = vTl + (size_t)group * 8 * 16384;
    f16* Preg = tile ? PB : PA;

    // Q fragments, scale folded
    f16x8 aq[2][4];
#pragma unroll
    for (int t = 0; t < 2; t++)
#pragma unroll
        for (int dk = 0; dk < 4; dk++) {
            int seg = (wq * 2 + t) * 4 + dk;
            f16x8 v = *(const f16x8*)(qb + seg * 512 + lane * 8);
            aq[t][dk] = v * (f16)0.08838834764831845f;
        }

    float m_i[2] = {-1e30f, -1e30f}, l_i[2] = {0.f, 0.f};
    f32x4 oaccT[2][8] = {};

    // staging role: waves 0-3 stage K, waves 4-7 stage V
    const f16* sbase = tile ? vb : kb;
    f16* dstL = tile ? Vl : Kl;
    f16x8 buf[8];
#pragma unroll
    for (int i = 0; i < 8; i++)
        buf[i] = *(const f16x8*)(sbase + (size_t)((wq * 8 + i) * 64 + lane) * 8);

    for (int mc = 0; mc < 8; mc++) {
        __syncthreads();  // (A) all prev-iter K/V reads done
#pragma unroll
        for (int i = 0; i < 8; i++)
            *(f16x8*)&dstL[(wq * 8 + i) * 512 + lane * 8] = buf[i];
        __syncthreads();  // (B) staged

        // S^T = K Q^T : D[m-local=quad*4+r][n-local=l15]
        f32x4 st[2][8] = {};
#pragma unroll
        for (int dk = 0; dk < 4; dk++) {
            f16x8 kf[8];
#pragma unroll
            for (int t = 0; t < 8; t++)
                kf[t] = *(const f16x8*)&Kl[(dk * 4 + quad) * 1024 + (t * 16 + l15) * 8];
#pragma unroll
            for (int tr = 0; tr < 2; tr++)
#pragma unroll
                for (int tc = 0; tc < 8; tc++)
                    st[tr][tc] = __builtin_amdgcn_mfma_f32_16x16x32_f16(kf[tc], aq[tr][dk], st[tr][tc], 0, 0, 0);
        }

        // online softmax: in-lane over 32 m-values + 2 shuffles
#pragma unroll
        for (int tr = 0; tr < 2; tr++) {
            float mx = -1e30f;
#pragma unroll
            for (int tc = 0; tc < 8; tc++)
#pragma unroll
                for (int r = 0; r < 4; r++) mx = fmaxf(mx, st[tr][tc][r]);
            mx = fmaxf(mx, __shfl_xor(mx, 16));
            mx = fmaxf(mx, __shfl_xor(mx, 32));
            float mnew = fmaxf(m_i[tr], mx);
            float alpha = __expf(m_i[tr] - mnew);
            m_i[tr] = mnew;
            float rs = 0.f;
#pragma unroll
            for (int tc = 0; tc < 8; tc++)
#pragma unroll
                for (int r = 0; r < 4; r++) {
                    float p = __expf(st[tr][tc][r] - mnew);
                    st[tr][tc][r] = p;
                    rs += p;
                }
            rs += __shfl_xor(rs, 16);
            rs += __shfl_xor(rs, 32);
            l_i[tr] = l_i[tr] * alpha + rs;
#pragma unroll
            for (int tc = 0; tc < 8; tc++) {
                oaccT[tr][tc].x *= alpha; oaccT[tr][tc].y *= alpha;
                oaccT[tr][tc].z *= alpha; oaccT[tr][tc].w *= alpha;
            }
        }

        // P[n][m] store into own per-tile region (wave-private rows, no barrier)
#pragma unroll
        for (int tr = 0; tr < 2; tr++) {
            int n = wq * 32 + tr * 16 + l15;
#pragma unroll
            for (int tc = 0; tc < 8; tc++) {
                int blk = tc * 2 + (quad >> 1);
                f16x4 pv;
#pragma unroll
                for (int r = 0; r < 4; r++) pv[r] = (f16)st[tr][tc][r];
                *(f16x4*)&Preg[n * 128 + ((blk ^ (n & 15)) << 3) + ((quad & 1) << 2)] = pv;
            }
        }

        // prefetch next K or V tile into registers (overlaps PV)
        if (mc < 7) {
            const f16* s = sbase + (size_t)(mc + 1) * 16384;
#pragma unroll
            for (int i = 0; i < 8; i++)
                buf[i] = *(const f16x8*)(s + (size_t)((wq * 8 + i) * 64 + lane) * 8);
        }

        // O^T += V^T P
#pragma unroll
        for (int mk = 0; mk < 4; mk++) {
            f16x8 vf[8], pf[2];
#pragma unroll
            for (int t = 0; t < 8; t++)
                vf[t] = *(const f16x8*)&Vl[(mk * 4 + quad) * 1024 + (t * 16 + l15) * 8];
#pragma unroll
            for (int tr = 0; tr < 2; tr++) {
                int n = wq * 32 + tr * 16 + l15;
                int blk = mk * 4 + quad;
                pf[tr] = *(const f16x8*)&Preg[n * 128 + ((blk ^ (n & 15)) << 3)];
            }
#pragma unroll
            for (int tr = 0; tr < 2; tr++)
#pragma unroll
                for (int tc = 0; tc < 8; tc++)
                    oaccT[tr][tc] = __builtin_amdgcn_mfma_f32_16x16x32_f16(vf[tc], pf[tr], oaccT[tr][tc], 0, 0, 0);
        }
    }

    // epilogue: O -> own P region (same swizzled layout, c in place of m),
    // then block-coalesced f16x8 global stores (full 64B lines -> no write amp).
#pragma unroll
    for (int tr = 0; tr < 2; tr++) {
        float inv = 1.f / l_i[tr];
        int n = wq * 32 + tr * 16 + l15;
#pragma unroll
        for (int tc = 0; tc < 8; tc++) {
            int blk = tc * 2 + (quad >> 1);
            f16x4 ov;
#pragma unroll
            for (int r = 0; r < 4; r++) ov[r] = (f16)(oaccT[tr][tc][r] * inv);
            *(f16x4*)&Preg[n * 128 + ((blk ^ (n & 15)) << 3) + ((quad & 1) << 2)] = ov;
        }
    }
    __syncthreads();
    // waves 0-3 store tile A from PA; waves 4-7 store tile B from PB
    f16* ob = oT + ((size_t)(b * 8 + nt)) * 65536;
    int t256 = tid & 255;
#pragma unroll
    for (int i = 0; i < 8; i++) {
        int cid = t256 + i * 256;              // 0..2047
        int cbl = cid >> 7, n = cid & 127;
        f16x8 v = *(const f16x8*)&Preg[n * 128 + ((cbl ^ (n & 15)) << 3)];
        *(f16x8*)(ob + (size_t)(h * 16 + cbl) * 1024 + n * 8) = v;
    }
}

// ---------------- K4: proj GEMM + bias + residual -> fp32 out ----------------
__global__ __launch_bounds__(256, 2) void k_proj(const f16* __restrict__ wT, const float* __restrict__ bias,
                                                 const f16* __restrict__ oT, const float* __restrict__ x,
                                                 float* __restrict__ out) {
    int nt = blockIdx.x, ot = blockIdx.y, b = blockIdx.z;
    int n0 = nt * 128, o0 = ot * 128;
    __shared__ union SM {
        struct { f16 As[8192]; f16 Bs[8192]; } s;
        f16 Cs[128][136];
    } sm;
    __shared__ float biasS[128];
    if (threadIdx.x < 128) biasS[threadIdx.x] = bias[o0 + threadIdx.x];
    int tid = threadIdx.x, lane = tid & 63, wv = tid >> 6;
    int wr = wv >> 1, wc = wv & 1;
    int l15 = lane & 15, quad = lane >> 4;
    const f16* wA = wT + (size_t)ot * 65536;
    const f16* xB = oT + ((size_t)(b * 8 + nt)) * 65536;
    f32x4 acc[4][4] = {};
    f16x8 abuf[4], bbuf[4];
#pragma unroll
    for (int i = 0; i < 4; i++) {
        int s = wv * 4 + i;
        abuf[i] = *(const f16x8*)(wA + (size_t)(s * 64 + lane) * 8);
        bbuf[i] = *(const f16x8*)(xB + (size_t)(s * 64 + lane) * 8);
    }
    for (int kk = 0; kk < CH; kk += 64) {
        __syncthreads();
#pragma unroll
        for (int i = 0; i < 4; i++) {
            int s = wv * 4 + i;
            *(f16x8*)&sm.s.As[(s * 64 + lane) * 8] = abuf[i];
            *(f16x8*)&sm.s.Bs[(s * 64 + lane) * 8] = bbuf[i];
        }
        __syncthreads();
        if (kk < CH - 64) {
            const f16* sa = wA + (size_t)((kk + 64) >> 3) * 1024;
            const f16* sb = xB + (size_t)((kk + 64) >> 3) * 1024;
#pragma unroll
            for (int i = 0; i < 4; i++) {
                int s = wv * 4 + i;
                abuf[i] = *(const f16x8*)(sa + (size_t)(s * 64 + lane) * 8);
                bbuf[i] = *(const f16x8*)(sb + (size_t)(s * 64 + lane) * 8);
            }
        }
#pragma unroll
        for (int dk = 0; dk < 2; dk++) {
            f16x8 af[4], bf[4];
#pragma unroll
            for (int t = 0; t < 4; t++) {
                af[t] = *(const f16x8*)(sm.s.As + (dk * 4 + quad) * 1024 + (wr * 64 + t * 16 + l15) * 8);
                bf[t] = *(const f16x8*)(sm.s.Bs + (dk * 4 + quad) * 1024 + (wc * 64 + t * 16 + l15) * 8);
            }
#pragma unroll
            for (int tm = 0; tm < 4; tm++)
#pragma unroll
                for (int tn = 0; tn < 4; tn++)
                    acc[tm][tn] = __builtin_amdgcn_mfma_f32_16x16x32_f16(af[tm], bf[tn], acc[tm][tn], 0, 0, 0);
        }
    }
    __syncthreads();
#pragma unroll
    for (int tm = 0; tm < 4; tm++)
#pragma unroll
        for (int tn = 0; tn < 4; tn++)
#pragma unroll
            for (int r = 0; r < 4; r++) {
                int o = wr * 64 + tm * 16 + quad * 4 + r;
                int n = wc * 64 + tn * 16 + l15;
                sm.Cs[o][n] = (f16)(acc[tm][tn][r] + biasS[o]);
            }
    __syncthreads();
#pragma unroll
    for (int i = 0; i < 8; i++) {
        int cid = tid + i * 256;
        int row = cid >> 4, off = (cid & 15) * 8;
        f16x8 v = *(const f16x8*)&sm.Cs[row][off];
        size_t gofs = ((size_t)(b * CH) + o0 + row) * NPIX + n0 + off;
        const float* xp = x + gofs;
        float* op = out + gofs;
        f32x4 o0v, o1v;
        o0v.x = xp[0] + (float)v[0]; o0v.y = xp[1] + (float)v[1];
        o0v.z = xp[2] + (float)v[2]; o0v.w = xp[3] + (float)v[3];
        o1v.x = xp[4] + (float)v[4]; o1v.y = xp[5] + (float)v[5];
        o1v.z = xp[6] + (float)v[6]; o1v.w = xp[7] + (float)v[7];
        *(f32x4*)op = o0v; *(f32x4*)(op + 4) = o1v;
    }
}

extern "C" void kernel_launch(void* const* d_in, const int* in_sizes, int n_in,
                              void* d_out, int out_size, void* d_ws, size_t ws_size,
                              hipStream_t stream) {
    const float* x     = (const float*)d_in[0];
    const float* gamma = (const float*)d_in[1];
    const float* beta  = (const float*)d_in[2];
    const float* wqkv  = (const float*)d_in[3];
    const float* bqkv  = (const float*)d_in[4];
    const float* wproj = (const float*)d_in[5];
    const float* bproj = (const float*)d_in[6];
    float* out = (float*)d_out;

    char* p = (char*)d_ws;
    float2* stats = (float2*)p;   p += 16 * 32 * sizeof(float2);
    f16* wqT = (f16*)p;           p += (size_t)3 * CH * CH * 2;
    f16* wpT = (f16*)p;           p += (size_t)CH * CH * 2;
    f16* xnT = (f16*)p;           p += (size_t)BATCH * NPIX * CH * 2;
    f16* qF  = (f16*)p;           p += (size_t)BATCH * HEADS * NPIX * HD * 2;
    f16* kTl = (f16*)p;           p += (size_t)BATCH * HEADS * NPIX * HD * 2;
    f16* vTl = (f16*)p;           p += (size_t)BATCH * HEADS * NPIX * HD * 2;
    f16* oT  = (f16*)p;           p += (size_t)BATCH * NPIX * CH * 2;

    k_convert<<<dim3(384), 256, 0, stream>>>(wqkv, wproj, wqT, wpT);
    k_stats<<<dim3(BATCH * GROUPS), 256, 0, stream>>>(x, stats);
    k_norm_t<<<dim3(8, BATCH), 256, 0, stream>>>(x, gamma, beta, stats, xnT);
    k_qkv<<<dim3(8, 12, BATCH), 256, 0, stream>>>(wqT, bqkv, xnT, qF, kTl, vTl);

    hipFuncSetAttribute((const void*)k_attn, hipFuncAttributeMaxDynamicSharedMemorySize, 131072);
    k_attn<<<dim3(256), 512, 131072, stream>>>(qF, kTl, vTl, oT);

    k_proj<<<dim3(8, 4, BATCH), 256, 0, stream>>>(wpT, bproj, oT, x, out);
}

// Round 7
// 222.641 us; speedup vs baseline: 1.9350x; 1.1224x over previous
//
#include <hip/hip_runtime.h>

#define CH 512
#define HEADS 4
#define HD 128
#define NPIX 1024
#define BATCH 16
#define GROUPS 32
#define GSZ 16
#define EPS 1e-5f

typedef _Float16 f16;
typedef _Float16 f16x8 __attribute__((ext_vector_type(8)));
typedef _Float16 f16x4 __attribute__((ext_vector_type(4)));
typedef float f32x4 __attribute__((ext_vector_type(4)));

__device__ __forceinline__ void gld16(const f16* g, f16* l) {
    __builtin_amdgcn_global_load_lds((__attribute__((address_space(1))) const void*)g,
                                     (__attribute__((address_space(3))) void*)l, 16, 0, 0);
}

// ---------------- K0: convert + pre-transpose weights ----------------
__global__ void k_convert(const float* __restrict__ wq, const float* __restrict__ wp,
                          f16* __restrict__ wqT, f16* __restrict__ wpT) {
    int c = blockIdx.x * 256 + threadIdx.x;
    {
        int ot = c >> 13, kbl = (c >> 7) & 63, ol = c & 127;
        const float* s = wq + ((size_t)(ot * 128 + ol)) * CH + kbl * 8;
        f32x4 a = *(const f32x4*)s, b = *(const f32x4*)(s + 4);
        f16x8 v;
        v[0] = (f16)a.x; v[1] = (f16)a.y; v[2] = (f16)a.z; v[3] = (f16)a.w;
        v[4] = (f16)b.x; v[5] = (f16)b.y; v[6] = (f16)b.z; v[7] = (f16)b.w;
        *(f16x8*)(wqT + (size_t)c * 8) = v;
    }
    if (c < 32768) {
        int ot = c >> 13, kbl = (c >> 7) & 63, ol = c & 127;
        const float* s = wp + ((size_t)(ot * 128 + ol)) * CH + kbl * 8;
        f32x4 a = *(const f32x4*)s, b = *(const f32x4*)(s + 4);
        f16x8 v;
        v[0] = (f16)a.x; v[1] = (f16)a.y; v[2] = (f16)a.z; v[3] = (f16)a.w;
        v[4] = (f16)b.x; v[5] = (f16)b.y; v[6] = (f16)b.z; v[7] = (f16)b.w;
        *(f16x8*)(wpT + (size_t)c * 8) = v;
    }
}

// ---------------- K1a: groupnorm stats ----------------
__global__ void k_stats(const float* __restrict__ x, float2* __restrict__ stats) {
    int bg = blockIdx.x;
    const f32x4* b4 = (const f32x4*)(x + (size_t)bg * (GSZ * NPIX));
    float s = 0.f, ss = 0.f;
    for (int i = threadIdx.x; i < GSZ * NPIX / 4; i += 256) {
        f32x4 v = b4[i];
        s  += v.x + v.y + v.z + v.w;
        ss += v.x * v.x + v.y * v.y + v.z * v.z + v.w * v.w;
    }
    for (int off = 32; off; off >>= 1) { s += __shfl_down(s, off); ss += __shfl_down(ss, off); }
    __shared__ float as_[4], ass[4];
    int wv = threadIdx.x >> 6, ln = threadIdx.x & 63;
    if (ln == 0) { as_[wv] = s; ass[wv] = ss; }
    __syncthreads();
    if (threadIdx.x == 0) {
        float S = as_[0] + as_[1] + as_[2] + as_[3];
        float SS = ass[0] + ass[1] + ass[2] + ass[3];
        float mu = S / (GSZ * NPIX);
        float var = SS / (GSZ * NPIX) - mu * mu;
        stats[bg] = make_float2(mu, rsqrtf(var + EPS));
    }
}

// ---------------- K1b: normalize + transpose via in-register 8x4, no LDS ----------------
// grid (8 nt, 2 c-half, 16 b); thread handles 8c x 4n per iter, 4 iters.
__global__ void k_norm_t(const float* __restrict__ x, const float* __restrict__ gamma,
                         const float* __restrict__ beta, const float2* __restrict__ stats,
                         f16* __restrict__ xnT) {
    int nt = blockIdx.x, ch = blockIdx.y, b = blockIdx.z;
    int t = threadIdx.x;
    int nl = (t & 31) * 4;
    int cl = (t >> 5) * 8;
    f16* tb = xnT + ((size_t)(b * 8 + nt)) * 65536;
#pragma unroll
    for (int it = 0; it < 4; it++) {
        int c8 = ch * 256 + it * 64 + cl;
        float2 stv = stats[b * GROUPS + (c8 >> 4)];
        f32x4 ga = *(const f32x4*)(gamma + c8), gb = *(const f32x4*)(gamma + c8 + 4);
        f32x4 ba = *(const f32x4*)(beta + c8),  bb = *(const f32x4*)(beta + c8 + 4);
        float gs[8] = {ga.x, ga.y, ga.z, ga.w, gb.x, gb.y, gb.z, gb.w};
        float bs[8] = {ba.x, ba.y, ba.z, ba.w, bb.x, bb.y, bb.z, bb.w};
#pragma unroll
        for (int i = 0; i < 8; i++) { gs[i] *= stv.y; bs[i] = bs[i] - stv.x * gs[i]; }
        f16x4 h[8];
#pragma unroll
        for (int i = 0; i < 8; i++) {
            f32x4 v = *(const f32x4*)(x + ((size_t)(b * CH + c8 + i)) * NPIX + nt * 128 + nl);
            h[i][0] = (f16)(v.x * gs[i] + bs[i]);
            h[i][1] = (f16)(v.y * gs[i] + bs[i]);
            h[i][2] = (f16)(v.z * gs[i] + bs[i]);
            h[i][3] = (f16)(v.w * gs[i] + bs[i]);
        }
#pragma unroll
        for (int j = 0; j < 4; j++) {
            f16x8 o_;
#pragma unroll
            for (int i = 0; i < 8; i++) o_[i] = h[i][j];
            *(f16x8*)(tb + (size_t)(c8 >> 3) * 1024 + (nl + j) * 8) = o_;
        }
    }
}

// ---------------- K2: QKV GEMM, BK=64, async gld16 staging, 3 blocks/CU ----------------
__global__ __launch_bounds__(256, 3) void k_qkv(const f16* __restrict__ wT, const float* __restrict__ bias,
                                                const f16* __restrict__ xnT, f16* __restrict__ qF,
                                                f16* __restrict__ kTl, f16* __restrict__ vTl) {
    int nt = blockIdx.x, ot = blockIdx.y, b = blockIdx.z;
    int o0 = ot * 128;
    __shared__ union SM {
        struct { f16 As[8192]; f16 Bs[8192]; } s;
        f16 Cf[16384];
    } sm;
    __shared__ float biasS[128];
    if (threadIdx.x < 128) biasS[threadIdx.x] = bias[o0 + threadIdx.x];
    int tid = threadIdx.x, lane = tid & 63, wv = tid >> 6;
    int wr = wv >> 1, wc = wv & 1;
    int l15 = lane & 15, quad = lane >> 4;
    const f16* wA = wT + (size_t)ot * 65536;
    const f16* xB = xnT + ((size_t)(b * 8 + nt)) * 65536;
    f32x4 acc[4][4] = {};
    for (int kk = 0; kk < CH; kk += 64) {
        __syncthreads();
        const f16* sa = wA + (size_t)(kk >> 3) * 1024;
        const f16* sb = xB + (size_t)(kk >> 3) * 1024;
#pragma unroll
        for (int i = 0; i < 4; i++) {
            int s = wv * 4 + i;
            gld16(sa + (size_t)(s * 64 + lane) * 8, sm.s.As + s * 512);
            gld16(sb + (size_t)(s * 64 + lane) * 8, sm.s.Bs + s * 512);
        }
        __syncthreads();
#pragma unroll
        for (int dk = 0; dk < 2; dk++) {
            f16x8 af[4], bf[4];
#pragma unroll
            for (int t = 0; t < 4; t++) {
                af[t] = *(const f16x8*)(sm.s.As + (dk * 4 + quad) * 1024 + (wr * 64 + t * 16 + l15) * 8);
                bf[t] = *(const f16x8*)(sm.s.Bs + (dk * 4 + quad) * 1024 + (wc * 64 + t * 16 + l15) * 8);
            }
#pragma unroll
            for (int tm = 0; tm < 4; tm++)
#pragma unroll
                for (int tn = 0; tn < 4; tn++)
                    acc[tm][tn] = __builtin_amdgcn_mfma_f32_16x16x32_f16(af[tm], bf[tn], acc[tm][tn], 0, 0, 0);
        }
    }
    __syncthreads();
    int which = ot >> 2, h = ot & 3;
#pragma unroll
    for (int tm = 0; tm < 4; tm++)
#pragma unroll
        for (int tn = 0; tn < 4; tn++) {
            int ob = wr * 64 + tm * 16 + quad * 4;     // o base (r contiguous)
            int n  = wc * 64 + tn * 16 + l15;
            f16x4 pv;
#pragma unroll
            for (int r = 0; r < 4; r++) pv[r] = (f16)(acc[tm][tn][r] + biasS[ob + r]);
            if (which == 0) {
                int addr = ((((n >> 5) * 2 + ((n >> 4) & 1)) * 4 + (ob >> 5)) * 512)
                         + ((ob >> 3) & 3) * 128 + (n & 15) * 8 + (quad & 1) * 4;
                *(f16x4*)&sm.Cf[addr] = pv;
            } else if (which == 1) {
                int addr = (ob >> 3) * 1024 + n * 8 + (quad & 1) * 4;
                *(f16x4*)&sm.Cf[addr] = pv;
            } else {
#pragma unroll
                for (int r = 0; r < 4; r++)
                    sm.Cf[(n >> 3) * 1024 + (ob + r) * 8 + (n & 7)] = pv[r];
            }
        }
    __syncthreads();
    f16* tb = (which == 0) ? (qF + ((size_t)((b * 4 + h) * 8 + nt)) * 16384)
            : (which == 1) ? (kTl + ((size_t)((b * 4 + h) * 8 + nt)) * 16384)
                           : (vTl + ((size_t)((b * 4 + h) * 8 + nt)) * 16384);
#pragma unroll
    for (int i = 0; i < 8; i++) {
        int cid = tid + i * 256;
        *(f16x8*)(tb + (size_t)cid * 8) = *(const f16x8*)(sm.Cf + cid * 8);
    }
}

// ---------------- K3: flash attention v6.1 (tree reductions) ----------------
// 512 threads; one K/V stage serves two Q-tiles; P per-tile; coalesced epilogue.
// LDS: Kl 32K + Vl 32K + PA 32K + PB 32K = 128 KB -> 1 block/CU.
__global__ __launch_bounds__(512, 1) void k_attn(const f16* __restrict__ qF, const f16* __restrict__ kTl,
                                                 const f16* __restrict__ vTl, f16* __restrict__ oT) {
    int bid = blockIdx.x;
    int ntp = bid >> 6, group = bid & 63;
    int b = group >> 2, h = group & 3;
    extern __shared__ f16 smem[];
    f16* Kl = smem;
    f16* Vl = smem + 16384;
    f16* PA = smem + 32768;
    f16* PB = smem + 49152;
    int tid = threadIdx.x, lane = tid & 63, wv = tid >> 6;
    int wq = wv & 3;
    int tile = wv >> 2;
    int nt = ntp * 2 + tile;
    int l15 = lane & 15, quad = lane >> 4;
    const f16* qb = qF + ((size_t)(group * 8 + nt)) * 16384;
    const f16* kb = kTl + (size_t)group * 8 * 16384;
    const f16* vb = vTl + (size_t)group * 8 * 16384;
    f16* Preg = tile ? PB : PA;

    f16x8 aq[2][4];
#pragma unroll
    for (int t = 0; t < 2; t++)
#pragma unroll
        for (int dk = 0; dk < 4; dk++) {
            int seg = (wq * 2 + t) * 4 + dk;
            f16x8 v = *(const f16x8*)(qb + seg * 512 + lane * 8);
            aq[t][dk] = v * (f16)0.08838834764831845f;
        }

    float m_i[2] = {-1e30f, -1e30f}, l_i[2] = {0.f, 0.f};
    f32x4 oaccT[2][8] = {};

    const f16* sbase = tile ? vb : kb;
    f16* dstL = tile ? Vl : Kl;
    f16x8 buf[8];
#pragma unroll
    for (int i = 0; i < 8; i++)
        buf[i] = *(const f16x8*)(sbase + (size_t)((wq * 8 + i) * 64 + lane) * 8);

    for (int mc = 0; mc < 8; mc++) {
        __syncthreads();
#pragma unroll
        for (int i = 0; i < 8; i++)
            *(f16x8*)&dstL[(wq * 8 + i) * 512 + lane * 8] = buf[i];
        __syncthreads();

        // S^T = K Q^T
        f32x4 st[2][8] = {};
#pragma unroll
        for (int dk = 0; dk < 4; dk++) {
            f16x8 kf[8];
#pragma unroll
            for (int t = 0; t < 8; t++)
                kf[t] = *(const f16x8*)&Kl[(dk * 4 + quad) * 1024 + (t * 16 + l15) * 8];
#pragma unroll
            for (int tr = 0; tr < 2; tr++)
#pragma unroll
                for (int tc = 0; tc < 8; tc++)
                    st[tr][tc] = __builtin_amdgcn_mfma_f32_16x16x32_f16(kf[tc], aq[tr][dk], st[tr][tc], 0, 0, 0);
        }

        // online softmax: pairwise-tree in-lane reductions + 2 shuffles
#pragma unroll
        for (int tr = 0; tr < 2; tr++) {
            float a[8];
#pragma unroll
            for (int tc = 0; tc < 8; tc++)
                a[tc] = fmaxf(fmaxf(st[tr][tc][0], st[tr][tc][1]), fmaxf(st[tr][tc][2], st[tr][tc][3]));
#pragma unroll
            for (int s = 4; s; s >>= 1)
#pragma unroll
                for (int k = 0; k < 4; k++) if (k < s) a[k] = fmaxf(a[k], a[k + s]);
            float mx = a[0];
            mx = fmaxf(mx, __shfl_xor(mx, 16));
            mx = fmaxf(mx, __shfl_xor(mx, 32));
            float mnew = fmaxf(m_i[tr], mx);
            float alpha = __expf(m_i[tr] - mnew);
            m_i[tr] = mnew;
            float r4[8];
#pragma unroll
            for (int tc = 0; tc < 8; tc++) {
                float p0 = __expf(st[tr][tc][0] - mnew);
                float p1 = __expf(st[tr][tc][1] - mnew);
                float p2 = __expf(st[tr][tc][2] - mnew);
                float p3 = __expf(st[tr][tc][3] - mnew);
                st[tr][tc][0] = p0; st[tr][tc][1] = p1;
                st[tr][tc][2] = p2; st[tr][tc][3] = p3;
                r4[tc] = (p0 + p1) + (p2 + p3);
            }
#pragma unroll
            for (int s = 4; s; s >>= 1)
#pragma unroll
                for (int k = 0; k < 4; k++) if (k < s) r4[k] += r4[k + s];
            float rs = r4[0];
            rs += __shfl_xor(rs, 16);
            rs += __shfl_xor(rs, 32);
            l_i[tr] = l_i[tr] * alpha + rs;
#pragma unroll
            for (int tc = 0; tc < 8; tc++) {
                oaccT[tr][tc].x *= alpha; oaccT[tr][tc].y *= alpha;
                oaccT[tr][tc].z *= alpha; oaccT[tr][tc].w *= alpha;
            }
        }

        // P store (wave-private rows)
#pragma unroll
        for (int tr = 0; tr < 2; tr++) {
            int n = wq * 32 + tr * 16 + l15;
#pragma unroll
            for (int tc = 0; tc < 8; tc++) {
                int blk = tc * 2 + (quad >> 1);
                f16x4 pv;
#pragma unroll
                for (int r = 0; r < 4; r++) pv[r] = (f16)st[tr][tc][r];
                *(f16x4*)&Preg[n * 128 + ((blk ^ (n & 15)) << 3) + ((quad & 1) << 2)] = pv;
            }
        }

        // prefetch next K or V tile
        if (mc < 7) {
            const f16* s = sbase + (size_t)(mc + 1) * 16384;
#pragma unroll
            for (int i = 0; i < 8; i++)
                buf[i] = *(const f16x8*)(s + (size_t)((wq * 8 + i) * 64 + lane) * 8);
        }

        // O^T += V^T P
#pragma unroll
        for (int mk = 0; mk < 4; mk++) {
            f16x8 vf[8], pf[2];
#pragma unroll
            for (int t = 0; t < 8; t++)
                vf[t] = *(const f16x8*)&Vl[(mk * 4 + quad) * 1024 + (t * 16 + l15) * 8];
#pragma unroll
            for (int tr = 0; tr < 2; tr++) {
                int n = wq * 32 + tr * 16 + l15;
                int blk = mk * 4 + quad;
                pf[tr] = *(const f16x8*)&Preg[n * 128 + ((blk ^ (n & 15)) << 3)];
            }
#pragma unroll
            for (int tr = 0; tr < 2; tr++)
#pragma unroll
                for (int tc = 0; tc < 8; tc++)
                    oaccT[tr][tc] = __builtin_amdgcn_mfma_f32_16x16x32_f16(vf[tc], pf[tr], oaccT[tr][tc], 0, 0, 0);
        }
    }

    // epilogue: O -> own P region, then block-coalesced f16x8 stores
#pragma unroll
    for (int tr = 0; tr < 2; tr++) {
        float inv = 1.f / l_i[tr];
        int n = wq * 32 + tr * 16 + l15;
#pragma unroll
        for (int tc = 0; tc < 8; tc++) {
            int blk = tc * 2 + (quad >> 1);
            f16x4 ov;
#pragma unroll
            for (int r = 0; r < 4; r++) ov[r] = (f16)(oaccT[tr][tc][r] * inv);
            *(f16x4*)&Preg[n * 128 + ((blk ^ (n & 15)) << 3) + ((quad & 1) << 2)] = ov;
        }
    }
    __syncthreads();
    f16* ob = oT + ((size_t)(b * 8 + nt)) * 65536;
    int t256 = tid & 255;
#pragma unroll
    for (int i = 0; i < 8; i++) {
        int cid = t256 + i * 256;
        int cbl = cid >> 7, n = cid & 127;
        f16x8 v = *(const f16x8*)&Preg[n * 128 + ((cbl ^ (n & 15)) << 3)];
        *(f16x8*)(ob + (size_t)(h * 16 + cbl) * 1024 + n * 8) = v;
    }
}

// ---------------- K4: proj GEMM + bias + residual -> fp32 out ----------------
__global__ __launch_bounds__(256, 3) void k_proj(const f16* __restrict__ wT, const float* __restrict__ bias,
                                                 const f16* __restrict__ oT, const float* __restrict__ x,
                                                 float* __restrict__ out) {
    int nt = blockIdx.x, ot = blockIdx.y, b = blockIdx.z;
    int n0 = nt * 128, o0 = ot * 128;
    __shared__ union SM {
        struct { f16 As[8192]; f16 Bs[8192]; } s;
        f16 Cs[128][136];
    } sm;
    __shared__ float biasS[128];
    if (threadIdx.x < 128) biasS[threadIdx.x] = bias[o0 + threadIdx.x];
    int tid = threadIdx.x, lane = tid & 63, wv = tid >> 6;
    int wr = wv >> 1, wc = wv & 1;
    int l15 = lane & 15, quad = lane >> 4;
    const f16* wA = wT + (size_t)ot * 65536;
    const f16* xB = oT + ((size_t)(b * 8 + nt)) * 65536;
    f32x4 acc[4][4] = {};
    for (int kk = 0; kk < CH; kk += 64) {
        __syncthreads();
        const f16* sa = wA + (size_t)(kk >> 3) * 1024;
        const f16* sb = xB + (size_t)(kk >> 3) * 1024;
#pragma unroll
        for (int i = 0; i < 4; i++) {
            int s = wv * 4 + i;
            gld16(sa + (size_t)(s * 64 + lane) * 8, sm.s.As + s * 512);
            gld16(sb + (size_t)(s * 64 + lane) * 8, sm.s.Bs + s * 512);
        }
        __syncthreads();
#pragma unroll
        for (int dk = 0; dk < 2; dk++) {
            f16x8 af[4], bf[4];
#pragma unroll
            for (int t = 0; t < 4; t++) {
                af[t] = *(const f16x8*)(sm.s.As + (dk * 4 + quad) * 1024 + (wr * 64 + t * 16 + l15) * 8);
                bf[t] = *(const f16x8*)(sm.s.Bs + (dk * 4 + quad) * 1024 + (wc * 64 + t * 16 + l15) * 8);
            }
#pragma unroll
            for (int tm = 0; tm < 4; tm++)
#pragma unroll
                for (int tn = 0; tn < 4; tn++)
                    acc[tm][tn] = __builtin_amdgcn_mfma_f32_16x16x32_f16(af[tm], bf[tn], acc[tm][tn], 0, 0, 0);
        }
    }
    __syncthreads();
#pragma unroll
    for (int tm = 0; tm < 4; tm++)
#pragma unroll
        for (int tn = 0; tn < 4; tn++)
#pragma unroll
            for (int r = 0; r < 4; r++) {
                int o = wr * 64 + tm * 16 + quad * 4 + r;
                int n = wc * 64 + tn * 16 + l15;
                sm.Cs[o][n] = (f16)(acc[tm][tn][r] + biasS[o]);
            }
    __syncthreads();
#pragma unroll
    for (int i = 0; i < 8; i++) {
        int cid = tid + i * 256;
        int row = cid >> 4, off = (cid & 15) * 8;
        f16x8 v = *(const f16x8*)&sm.Cs[row][off];
        size_t gofs = ((size_t)(b * CH) + o0 + row) * NPIX + n0 + off;
        const float* xp = x + gofs;
        float* op = out + gofs;
        f32x4 o0v, o1v;
        o0v.x = xp[0] + (float)v[0]; o0v.y = xp[1] + (float)v[1];
        o0v.z = xp[2] + (float)v[2]; o0v.w = xp[3] + (float)v[3];
        o1v.x = xp[4] + (float)v[4]; o1v.y = xp[5] + (float)v[5];
        o1v.z = xp[6] + (float)v[6]; o1v.w = xp[7] + (float)v[7];
        *(f32x4*)op = o0v; *(f32x4*)(op + 4) = o1v;
    }
}

extern "C" void kernel_launch(void* const* d_in, const int* in_sizes, int n_in,
                              void* d_out, int out_size, void* d_ws, size_t ws_size,
                              hipStream_t stream) {
    const float* x     = (const float*)d_in[0];
    const float* gamma = (const float*)d_in[1];
    const float* beta  = (const float*)d_in[2];
    const float* wqkv  = (const float*)d_in[3];
    const float* bqkv  = (const float*)d_in[4];
    const float* wproj = (const float*)d_in[5];
    const float* bproj = (const float*)d_in[6];
    float* out = (float*)d_out;

    char* p = (char*)d_ws;
    float2* stats = (float2*)p;   p += 16 * 32 * sizeof(float2);
    f16* wqT = (f16*)p;           p += (size_t)3 * CH * CH * 2;
    f16* wpT = (f16*)p;           p += (size_t)CH * CH * 2;
    f16* xnT = (f16*)p;           p += (size_t)BATCH * NPIX * CH * 2;
    f16* qF  = (f16*)p;           p += (size_t)BATCH * HEADS * NPIX * HD * 2;
    f16* kTl = (f16*)p;           p += (size_t)BATCH * HEADS * NPIX * HD * 2;
    f16* vTl = (f16*)p;           p += (size_t)BATCH * HEADS * NPIX * HD * 2;
    f16* oT  = (f16*)p;           p += (size_t)BATCH * NPIX * CH * 2;

    k_convert<<<dim3(384), 256, 0, stream>>>(wqkv, wproj, wqT, wpT);
    k_stats<<<dim3(BATCH * GROUPS), 256, 0, stream>>>(x, stats);
    k_norm_t<<<dim3(8, 2, BATCH), 256, 0, stream>>>(x, gamma, beta, stats, xnT);
    k_qkv<<<dim3(8, 12, BATCH), 256, 0, stream>>>(wqT, bqkv, xnT, qF, kTl, vTl);

    hipFuncSetAttribute((const void*)k_attn, hipFuncAttributeMaxDynamicSharedMemorySize, 131072);
    k_attn<<<dim3(256), 512, 131072, stream>>>(qF, kTl, vTl, oT);

    k_proj<<<dim3(8, 4, BATCH), 256, 0, stream>>>(wpT, bproj, oT, x, out);
}